// Round 1
// baseline (902.581 us; speedup 1.0000x reference)
//
#include <hip/hip_runtime.h>
#include <math.h>

#define N_NODES 20000
#define E_EDGES 320000
#define IN_CH   300
#define HID     100
#define R_REL   50
#define NB      8
#define CLS     3
#define NQ      64
#define EPS_F   1e-16f
#define OUTW    800   // NB * HID

// ---- monotone float<->unsigned key for atomicMax-based segment max ----
__device__ __forceinline__ unsigned fkey(float f) {
    unsigned b = __float_as_uint(f);
    return (b & 0x80000000u) ? ~b : (b | 0x80000000u);
}
__device__ __forceinline__ float unkey(unsigned k) {
    return __uint_as_float((k & 0x80000000u) ? (k & 0x7FFFFFFFu) : ~k);
}

// ---- transpose basis [B, K, HID] -> Bw [K, B*HID] so GEMM B-loads coalesce ----
__global__ __launch_bounds__(256) void transpose_basis(
        const float* __restrict__ basis, float* __restrict__ Bw, int kdim) {
    int idx = blockIdx.x * 256 + threadIdx.x;
    int total = kdim * OUTW;
    if (idx >= total) return;
    int i   = idx / OUTW;      // k index
    int col = idx % OUTW;      // b*HID + o
    int b = col / HID, o = col % HID;
    Bw[idx] = basis[(b * kdim + i) * HID + o];
}

// ---- fp32 tiled GEMM: C[n,800] = A[n,k] * Bw[k,800] ----
#define BM 64
#define BN 64
#define BK 16
__global__ __launch_bounds__(256) void gemm_kernel(
        const float* __restrict__ A, const float* __restrict__ B,
        float* __restrict__ C, int n, int k) {
    __shared__ float As[BK][BM + 4];
    __shared__ float Bs[BK][BN + 4];
    int tid = threadIdx.x;
    int tx = tid & 15, ty = tid >> 4;
    int row0 = blockIdx.y * BM;
    int col0 = blockIdx.x * BN;
    float acc[4][4] = {};
    for (int k0 = 0; k0 < k; k0 += BK) {
        #pragma unroll
        for (int i = 0; i < 4; i++) {
            int id = tid + i * 256;
            int am = id >> 4, ak = id & 15;
            int gr = row0 + am, gk = k0 + ak;
            float v = 0.f;
            if (gr < n && gk < k) v = A[gr * k + gk];
            As[ak][am] = v;
        }
        #pragma unroll
        for (int i = 0; i < 4; i++) {
            int id = tid + i * 256;
            int bk = id >> 6, bn = id & 63;
            int gk = k0 + bk, gc = col0 + bn;
            float v = 0.f;
            if (gk < k && gc < OUTW) v = B[gk * OUTW + gc];
            Bs[bk][bn] = v;
        }
        __syncthreads();
        #pragma unroll
        for (int kk = 0; kk < BK; kk++) {
            float a4[4], b4[4];
            #pragma unroll
            for (int i = 0; i < 4; i++) a4[i] = As[kk][ty * 4 + i];
            #pragma unroll
            for (int j = 0; j < 4; j++) b4[j] = Bs[kk][tx * 4 + j];
            #pragma unroll
            for (int i = 0; i < 4; i++)
                #pragma unroll
                for (int j = 0; j < 4; j++)
                    acc[i][j] = fmaf(a4[i], b4[j], acc[i][j]);
        }
        __syncthreads();
    }
    #pragma unroll
    for (int i = 0; i < 4; i++) {
        int gr = row0 + ty * 4 + i;
        if (gr >= n) continue;
        #pragma unroll
        for (int j = 0; j < 4; j++) {
            int gc = col0 + tx * 4 + j;
            if (gc < OUTW) C[gr * OUTW + gc] = acc[i][j];
        }
    }
}

// ---- xbq[n,b] = xb[n,b,:] . q ; xbk likewise (xb[(n*8+b)*100+o]) ----
__global__ __launch_bounds__(256) void qk_kernel(
        const float* __restrict__ xb, const float* __restrict__ q,
        const float* __restrict__ k, float* __restrict__ xbq,
        float* __restrict__ xbk) {
    __shared__ float sq[HID], sk[HID];
    int tid = threadIdx.x;
    if (tid < HID) { sq[tid] = q[tid]; sk[tid] = k[tid]; }
    __syncthreads();
    int idx = blockIdx.x * 256 + tid;   // idx = n*NB + b
    if (idx >= N_NODES * NB) return;
    const float* base = xb + (size_t)idx * HID;
    float aq = 0.f, ak = 0.f;
    #pragma unroll 4
    for (int o = 0; o < HID; o++) {
        float v = base[o];
        aq = fmaf(v, sq[o], aq);
        ak = fmaf(v, sk[o], ak);
    }
    xbq[idx] = aq;
    xbk[idx] = ak;
}

__global__ __launch_bounds__(256) void init_node(unsigned* __restrict__ umax,
                                                 float* __restrict__ ssum) {
    int i = blockIdx.x * 256 + threadIdx.x;
    if (i < N_NODES) { umax[i] = 0u; ssum[i] = 0.f; }
}

__global__ __launch_bounds__(256) void init_h(float* __restrict__ h,
                                              const float* __restrict__ bias) {
    int i = blockIdx.x * 256 + threadIdx.x;
    if (i < N_NODES * HID) h[i] = bias[i % HID];
}

// ---- per-edge attention logit + segment max ----
__global__ __launch_bounds__(256) void edge1_kernel(
        const int* __restrict__ ei, const int* __restrict__ et,
        const float* __restrict__ comp, const float* __restrict__ xbq,
        const float* __restrict__ xbk, float* __restrict__ aE,
        unsigned* __restrict__ umax) {
    int e = blockIdx.x * 256 + threadIdx.x;
    if (e >= E_EDGES) return;
    int s = ei[e], d = ei[E_EDGES + e], rt = et[e];
    const float* c = comp + rt * NB;
    float qi = 0.f, kj = 0.f;
    #pragma unroll
    for (int b = 0; b < NB; b++) {
        float cb = c[b];
        qi = fmaf(cb, xbq[d * NB + b], qi);
        kj = fmaf(cb, xbk[s * NB + b], kj);
    }
    float a = qi + kj;
    a = a > 0.f ? a : 0.2f * a;           // leaky_relu 0.2
    aE[e] = a;
    atomicMax(&umax[d], fkey(a));
}

// ---- per-edge exp + segment sum ----
__global__ __launch_bounds__(256) void edge2_kernel(
        const int* __restrict__ ei, const float* __restrict__ aE,
        const unsigned* __restrict__ umax, float* __restrict__ eaE,
        float* __restrict__ ssum) {
    int e = blockIdx.x * 256 + threadIdx.x;
    if (e >= E_EDGES) return;
    int d = ei[E_EDGES + e];
    float m = unkey(umax[d]);
    float ex = __expf(aE[e] - m);
    eaE[e] = ex;
    atomicAdd(&ssum[d], ex);
}

// ---- message scatter: h[dst,o] += alpha * sum_b comp[rt,b]*xb[src,b,o] ----
__global__ __launch_bounds__(256) void msg_kernel(
        const int* __restrict__ ei, const int* __restrict__ et,
        const float* __restrict__ comp, const float* __restrict__ xb,
        const float* __restrict__ eaE, const float* __restrict__ ssum,
        float* __restrict__ h) {
    int tid = threadIdx.x;
    int e = blockIdx.x * 2 + (tid >> 7);
    int o = tid & 127;
    if (e >= E_EDGES || o >= HID) return;
    int s = ei[e], d = ei[E_EDGES + e], rt = et[e];
    float alpha = eaE[e] / (ssum[d] + EPS_F);
    const float* c = comp + rt * NB;
    const float* xs = xb + (size_t)s * OUTW + o;
    float m = 0.f;
    #pragma unroll
    for (int b = 0; b < NB; b++) m = fmaf(c[b], xs[b * HID], m);
    atomicAdd(&h[d * HID + o], alpha * m);
}

__global__ __launch_bounds__(256) void relu_kernel(float* __restrict__ h) {
    int i = blockIdx.x * 256 + threadIdx.x;
    if (i < N_NODES * HID) h[i] = fmaxf(h[i], 0.f);
}

// ---- pooled = mean(h2[qidx]); out = pooled @ Wl^T + bl ----
__global__ __launch_bounds__(128) void head_kernel(
        const float* __restrict__ h2, const int* __restrict__ qidx,
        const float* __restrict__ Wl, const float* __restrict__ bl,
        float* __restrict__ out) {
    __shared__ float pooled[HID];
    int tid = threadIdx.x;
    if (tid < HID) {
        float s = 0.f;
        for (int i = 0; i < NQ; i++) s += h2[(size_t)qidx[i] * HID + tid];
        pooled[tid] = s * (1.0f / NQ);
    }
    __syncthreads();
    if (tid < CLS) {
        float s = bl[tid];
        for (int o = 0; o < HID; o++) s = fmaf(pooled[o], Wl[tid * HID + o], s);
        out[tid] = s;
    }
}

extern "C" void kernel_launch(void* const* d_in, const int* in_sizes, int n_in,
                              void* d_out, int out_size, void* d_ws, size_t ws_size,
                              hipStream_t stream) {
    const float* x      = (const float*)d_in[0];
    const int*   ei     = (const int*)  d_in[1];
    const int*   et     = (const int*)  d_in[2];
    const int*   qidx   = (const int*)  d_in[3];
    const float* comp1  = (const float*)d_in[4];
    const float* basis1 = (const float*)d_in[5];
    const float* q1     = (const float*)d_in[6];
    const float* k1     = (const float*)d_in[7];
    const float* b1     = (const float*)d_in[8];
    const float* comp2  = (const float*)d_in[9];
    const float* basis2 = (const float*)d_in[10];
    const float* q2     = (const float*)d_in[11];
    const float* k2     = (const float*)d_in[12];
    const float* b2     = (const float*)d_in[13];
    const float* Wl     = (const float*)d_in[14];
    const float* bl     = (const float*)d_in[15];
    float* out = (float*)d_out;

    // workspace layout (floats), ~85 MB total
    char* w = (char*)d_ws;
    size_t off = 0;
    auto alloc = [&](size_t nfloats) {
        float* p = (float*)(w + off);
        off += ((nfloats * sizeof(float) + 255) / 256) * 256;
        return p;
    };
    float*    xb   = alloc((size_t)N_NODES * OUTW);  // 64 MB
    float*    h1   = alloc((size_t)N_NODES * HID);
    float*    h2   = alloc((size_t)N_NODES * HID);
    float*    xbq  = alloc((size_t)N_NODES * NB);
    float*    xbk  = alloc((size_t)N_NODES * NB);
    float*    aE   = alloc(E_EDGES);
    float*    eaE  = alloc(E_EDGES);
    unsigned* umax = (unsigned*)alloc(N_NODES);
    float*    ssum = alloc(N_NODES);
    float*    Bw   = alloc((size_t)IN_CH * OUTW);

    auto layer = [&](const float* input, int K, const float* comp,
                     const float* basis, const float* q, const float* k,
                     const float* bias, float* hout) {
        int tot = K * OUTW;
        transpose_basis<<<(tot + 255) / 256, 256, 0, stream>>>(basis, Bw, K);
        dim3 g((OUTW + BN - 1) / BN, (N_NODES + BM - 1) / BM);
        gemm_kernel<<<g, 256, 0, stream>>>(input, Bw, xb, N_NODES, K);
        qk_kernel<<<(N_NODES * NB + 255) / 256, 256, 0, stream>>>(xb, q, k, xbq, xbk);
        init_node<<<(N_NODES + 255) / 256, 256, 0, stream>>>(umax, ssum);
        init_h<<<(N_NODES * HID + 255) / 256, 256, 0, stream>>>(hout, bias);
        edge1_kernel<<<(E_EDGES + 255) / 256, 256, 0, stream>>>(ei, et, comp, xbq, xbk, aE, umax);
        edge2_kernel<<<(E_EDGES + 255) / 256, 256, 0, stream>>>(ei, aE, umax, eaE, ssum);
        msg_kernel<<<E_EDGES / 2, 256, 0, stream>>>(ei, et, comp, xb, eaE, ssum, hout);
        relu_kernel<<<(N_NODES * HID + 255) / 256, 256, 0, stream>>>(hout);
    };

    layer(x, IN_CH, comp1, basis1, q1, k1, b1, h1);
    layer(h1, HID, comp2, basis2, q2, k2, b2, h2);
    head_kernel<<<1, 128, 0, stream>>>(h2, qidx, Wl, bl, out);
}

// Round 2
// 682.090 us; speedup vs baseline: 1.3233x; 1.3233x over previous
//
#include <hip/hip_runtime.h>
#include <math.h>

#define N_NODES 20000
#define E_EDGES 320000
#define IN_CH   300
#define HID     100
#define R_REL   50
#define NB      8
#define CLS     3
#define NQ      64
#define EPS_F   1e-16f
#define OUTW    800   // NB * HID

typedef unsigned short ushort_t;
typedef __attribute__((ext_vector_type(8))) short     short8;
typedef __attribute__((ext_vector_type(8))) unsigned short ushort8;
typedef __attribute__((ext_vector_type(4))) float     f32x4;

// ---- monotone float<->unsigned key for atomicMax-based segment max ----
__device__ __forceinline__ unsigned fkey(float f) {
    unsigned b = __float_as_uint(f);
    return (b & 0x80000000u) ? ~b : (b | 0x80000000u);
}
__device__ __forceinline__ float unkey(unsigned k) {
    return __uint_as_float((k & 0x80000000u) ? (k & 0x7FFFFFFFu) : ~k);
}

__device__ __forceinline__ void split_f32(float v, ushort_t& hi, ushort_t& lo) {
    unsigned vb = __float_as_uint(v);
    hi = (ushort_t)(vb >> 16);                       // truncate to bf16
    float vh = __uint_as_float((unsigned)hi << 16);
    float l  = v - vh;                               // exact
    lo = (ushort_t)(__float_as_uint(l) >> 16);
}

// ---- split A [M,K] fp32 -> Ah/Al [M,Kp] bf16 (zero-padded), optional relu ----
__global__ __launch_bounds__(256) void split_a_kernel(
        const float* __restrict__ A, ushort_t* __restrict__ Ah,
        ushort_t* __restrict__ Al, int M, int K, int Kp, int do_relu) {
    int idx = blockIdx.x * 256 + threadIdx.x;
    if (idx >= M * Kp) return;
    int m = idx / Kp, k = idx - m * Kp;
    float v = 0.f;
    if (k < K) {
        v = A[(size_t)m * K + k];
        if (do_relu) v = fmaxf(v, 0.f);
    }
    ushort_t hi, lo;
    split_f32(v, hi, lo);
    Ah[idx] = hi; Al[idx] = lo;
}

// ---- basis [B,K,HID] -> Bt hi/lo [800, Kp] bf16, transposed + zero-padded ----
__global__ __launch_bounds__(256) void split_bt_kernel(
        const float* __restrict__ basis, ushort_t* __restrict__ Bth,
        ushort_t* __restrict__ Btl, int K, int Kp) {
    int idx = blockIdx.x * 256 + threadIdx.x;   // n*Kp + k
    if (idx >= OUTW * Kp) return;
    int n = idx / Kp, k = idx - n * Kp;
    int b = n / HID, o = n - b * HID;
    float v = 0.f;
    if (k < K) v = basis[((size_t)b * K + k) * HID + o];
    ushort_t hi, lo;
    split_f32(v, hi, lo);
    Bth[idx] = hi; Btl[idx] = lo;
}

// ---- MFMA GEMM: C[M,800] = A[M,Kp] * B[Kp,800], split-bf16 fp32-accurate ----
#define BM 128
#define BN 80
__global__ __launch_bounds__(256) void gemm_mfma(
        const ushort_t* __restrict__ Ah, const ushort_t* __restrict__ Al,
        const ushort_t* __restrict__ Bth, const ushort_t* __restrict__ Btl,
        float* __restrict__ C, int M, int Kp) {
    __shared__ ushort_t As_h[BM][40], As_l[BM][40];
    __shared__ ushort_t Bs_h[BN][40], Bs_l[BN][40];
    int tid  = threadIdx.x;
    int lane = tid & 63, wave = tid >> 6;
    int ml = lane & 15, quad = lane >> 4;
    int row0 = blockIdx.y * BM, col0 = blockIdx.x * BN;
    f32x4 acc[2][5] = {};
    int ksteps = Kp >> 5;
    for (int ks = 0; ks < ksteps; ks++) {
        int k0 = ks << 5;
        __syncthreads();
        // stage A: 128 rows x 32 ushorts, 4 chunks of 16B per row
        #pragma unroll
        for (int p = 0; p < 2; p++) {
            int ra = p * 64 + (tid >> 2), ch = tid & 3;
            int gr = row0 + ra;
            ushort8 vh = {0,0,0,0,0,0,0,0}, vl = {0,0,0,0,0,0,0,0};
            if (gr < M) {
                vh = *(const ushort8*)&Ah[(size_t)gr * Kp + k0 + ch * 8];
                vl = *(const ushort8*)&Al[(size_t)gr * Kp + k0 + ch * 8];
            }
            *(ushort8*)&As_h[ra][ch * 8] = vh;
            *(ushort8*)&As_l[ra][ch * 8] = vl;
        }
        // stage B: 80 rows x 4 chunks = 320 tasks
        for (int t = tid; t < 320; t += 256) {
            int rb = t >> 2, ch = t & 3;
            ushort8 vh = *(const ushort8*)&Bth[(size_t)(col0 + rb) * Kp + k0 + ch * 8];
            ushort8 vl = *(const ushort8*)&Btl[(size_t)(col0 + rb) * Kp + k0 + ch * 8];
            *(ushort8*)&Bs_h[rb][ch * 8] = vh;
            *(ushort8*)&Bs_l[rb][ch * 8] = vl;
        }
        __syncthreads();
        short8 ah[2], al[2], bh[5], bl5[5];
        #pragma unroll
        for (int mt = 0; mt < 2; mt++) {
            int r = wave * 32 + mt * 16 + ml;
            ah[mt] = *(const short8*)&As_h[r][quad * 8];
            al[mt] = *(const short8*)&As_l[r][quad * 8];
        }
        #pragma unroll
        for (int nt = 0; nt < 5; nt++) {
            int r = nt * 16 + ml;
            bh[nt]  = *(const short8*)&Bs_h[r][quad * 8];
            bl5[nt] = *(const short8*)&Bs_l[r][quad * 8];
        }
        #pragma unroll
        for (int mt = 0; mt < 2; mt++)
            #pragma unroll
            for (int nt = 0; nt < 5; nt++) {
                acc[mt][nt] = __builtin_amdgcn_mfma_f32_16x16x32_bf16(ah[mt], bh[nt],  acc[mt][nt], 0, 0, 0);
                acc[mt][nt] = __builtin_amdgcn_mfma_f32_16x16x32_bf16(al[mt], bh[nt],  acc[mt][nt], 0, 0, 0);
                acc[mt][nt] = __builtin_amdgcn_mfma_f32_16x16x32_bf16(ah[mt], bl5[nt], acc[mt][nt], 0, 0, 0);
            }
    }
    // epilogue: C/D layout col = lane&15, row = quad*4 + reg
    #pragma unroll
    for (int mt = 0; mt < 2; mt++) {
        #pragma unroll
        for (int nt = 0; nt < 5; nt++) {
            #pragma unroll
            for (int r = 0; r < 4; r++) {
                int grow = row0 + wave * 32 + mt * 16 + quad * 4 + r;
                if (grow < M)
                    C[(size_t)grow * OUTW + col0 + nt * 16 + ml] = acc[mt][nt][r];
            }
        }
    }
}

// ---- xbq[n,b] = xb[n,b,:] . q ; xbk likewise ----
__global__ __launch_bounds__(256) void qk_kernel(
        const float* __restrict__ xb, const float* __restrict__ q,
        const float* __restrict__ k, float* __restrict__ xbq,
        float* __restrict__ xbk) {
    __shared__ float sq[HID], sk[HID];
    int tid = threadIdx.x;
    if (tid < HID) { sq[tid] = q[tid]; sk[tid] = k[tid]; }
    __syncthreads();
    int idx = blockIdx.x * 256 + tid;   // idx = n*NB + b
    if (idx >= N_NODES * NB) return;
    const float* base = xb + (size_t)idx * HID;
    float aq = 0.f, ak = 0.f;
    #pragma unroll 4
    for (int o = 0; o < HID; o++) {
        float v = base[o];
        aq = fmaf(v, sq[o], aq);
        ak = fmaf(v, sk[o], ak);
    }
    xbq[idx] = aq;
    xbk[idx] = ak;
}

// ---- init h=bias, umax=0, ssum=0 in one kernel ----
__global__ __launch_bounds__(256) void init_all(
        float* __restrict__ h, const float* __restrict__ bias,
        unsigned* __restrict__ umax, float* __restrict__ ssum) {
    int i = blockIdx.x * 256 + threadIdx.x;
    if (i < N_NODES * HID) h[i] = bias[i % HID];
    if (i < N_NODES) { umax[i] = 0u; ssum[i] = 0.f; }
}

// ---- per-edge attention logit + segment max ----
__global__ __launch_bounds__(256) void edge1_kernel(
        const int* __restrict__ ei, const int* __restrict__ et,
        const float* __restrict__ comp, const float* __restrict__ xbq,
        const float* __restrict__ xbk, float* __restrict__ aE,
        unsigned* __restrict__ umax) {
    int e = blockIdx.x * 256 + threadIdx.x;
    if (e >= E_EDGES) return;
    int s = ei[e], d = ei[E_EDGES + e], rt = et[e];
    const float* c = comp + rt * NB;
    float qi = 0.f, kj = 0.f;
    #pragma unroll
    for (int b = 0; b < NB; b++) {
        float cb = c[b];
        qi = fmaf(cb, xbq[d * NB + b], qi);
        kj = fmaf(cb, xbk[s * NB + b], kj);
    }
    float a = qi + kj;
    a = a > 0.f ? a : 0.2f * a;           // leaky_relu 0.2
    aE[e] = a;
    atomicMax(&umax[d], fkey(a));
}

// ---- per-edge exp + segment sum ----
__global__ __launch_bounds__(256) void edge2_kernel(
        const int* __restrict__ ei, const float* __restrict__ aE,
        const unsigned* __restrict__ umax, float* __restrict__ eaE,
        float* __restrict__ ssum) {
    int e = blockIdx.x * 256 + threadIdx.x;
    if (e >= E_EDGES) return;
    int d = ei[E_EDGES + e];
    float m = unkey(umax[d]);
    float ex = __expf(aE[e] - m);
    eaE[e] = ex;
    atomicAdd(&ssum[d], ex);
}

// ---- message scatter: h[dst,o] += alpha * sum_b comp[rt,b]*xb[src,b,o] ----
__global__ __launch_bounds__(256) void msg_kernel(
        const int* __restrict__ ei, const int* __restrict__ et,
        const float* __restrict__ comp, const float* __restrict__ xb,
        const float* __restrict__ eaE, const float* __restrict__ ssum,
        float* __restrict__ h) {
    int tid = threadIdx.x;
    int e = blockIdx.x * 2 + (tid >> 7);
    int o = tid & 127;
    if (e >= E_EDGES || o >= HID) return;
    int s = ei[e], d = ei[E_EDGES + e], rt = et[e];
    float alpha = eaE[e] / (ssum[d] + EPS_F);
    const float* c = comp + rt * NB;
    const float* xs = xb + (size_t)s * OUTW + o;
    float m = 0.f;
    #pragma unroll
    for (int b = 0; b < NB; b++) m = fmaf(c[b], xs[b * HID], m);
    atomicAdd(&h[d * HID + o], alpha * m);
}

// ---- pooled = mean(relu(h2[qidx])); out = pooled @ Wl^T + bl ----
__global__ __launch_bounds__(128) void head_kernel(
        const float* __restrict__ h2, const int* __restrict__ qidx,
        const float* __restrict__ Wl, const float* __restrict__ bl,
        float* __restrict__ out) {
    __shared__ float pooled[HID];
    int tid = threadIdx.x;
    if (tid < HID) {
        float s = 0.f;
        for (int i = 0; i < NQ; i++)
            s += fmaxf(h2[(size_t)qidx[i] * HID + tid], 0.f);
        pooled[tid] = s * (1.0f / NQ);
    }
    __syncthreads();
    if (tid < CLS) {
        float s = bl[tid];
        for (int o = 0; o < HID; o++) s = fmaf(pooled[o], Wl[tid * HID + o], s);
        out[tid] = s;
    }
}

extern "C" void kernel_launch(void* const* d_in, const int* in_sizes, int n_in,
                              void* d_out, int out_size, void* d_ws, size_t ws_size,
                              hipStream_t stream) {
    const float* x      = (const float*)d_in[0];
    const int*   ei     = (const int*)  d_in[1];
    const int*   et     = (const int*)  d_in[2];
    const int*   qidx   = (const int*)  d_in[3];
    const float* comp1  = (const float*)d_in[4];
    const float* basis1 = (const float*)d_in[5];
    const float* q1     = (const float*)d_in[6];
    const float* k1     = (const float*)d_in[7];
    const float* b1     = (const float*)d_in[8];
    const float* comp2  = (const float*)d_in[9];
    const float* basis2 = (const float*)d_in[10];
    const float* q2     = (const float*)d_in[11];
    const float* k2     = (const float*)d_in[12];
    const float* b2     = (const float*)d_in[13];
    const float* Wl     = (const float*)d_in[14];
    const float* bl     = (const float*)d_in[15];
    float* out = (float*)d_out;

    const int KP1 = 320, KP2 = 128;

    char* w = (char*)d_ws;
    size_t off = 0;
    auto alloc = [&](size_t nbytes) {
        void* p = (void*)(w + off);
        off += ((nbytes + 255) / 256) * 256;
        return p;
    };
    float*    xb   = (float*)alloc((size_t)N_NODES * OUTW * 4);   // 64 MB
    float*    h1   = (float*)alloc((size_t)N_NODES * HID * 4);    // 8 MB
    float*    h2   = (float*)alloc((size_t)N_NODES * HID * 4);    // 8 MB
    ushort_t* Ah   = (ushort_t*)alloc((size_t)N_NODES * KP1 * 2); // 12.8 MB
    ushort_t* Al   = (ushort_t*)alloc((size_t)N_NODES * KP1 * 2); // 12.8 MB
    ushort_t* Bth  = (ushort_t*)alloc((size_t)OUTW * KP1 * 2);
    ushort_t* Btl  = (ushort_t*)alloc((size_t)OUTW * KP1 * 2);
    float*    xbq  = (float*)alloc((size_t)N_NODES * NB * 4);
    float*    xbk  = (float*)alloc((size_t)N_NODES * NB * 4);
    float*    aE   = (float*)alloc(E_EDGES * 4);
    float*    eaE  = (float*)alloc(E_EDGES * 4);
    unsigned* umax = (unsigned*)alloc(N_NODES * 4);
    float*    ssum = (float*)alloc(N_NODES * 4);

    auto layer = [&](const float* input, int K, int Kp, int relu_in,
                     const float* comp, const float* basis, const float* q,
                     const float* k, const float* bias, float* hout) {
        int na = N_NODES * Kp;
        split_a_kernel<<<(na + 255) / 256, 256, 0, stream>>>(input, Ah, Al, N_NODES, K, Kp, relu_in);
        int nb = OUTW * Kp;
        split_bt_kernel<<<(nb + 255) / 256, 256, 0, stream>>>(basis, Bth, Btl, K, Kp);
        dim3 g(OUTW / BN, (N_NODES + BM - 1) / BM);
        gemm_mfma<<<g, 256, 0, stream>>>(Ah, Al, Bth, Btl, xb, N_NODES, Kp);
        qk_kernel<<<(N_NODES * NB + 255) / 256, 256, 0, stream>>>(xb, q, k, xbq, xbk);
        init_all<<<(N_NODES * HID + 255) / 256, 256, 0, stream>>>(hout, bias, umax, ssum);
        edge1_kernel<<<(E_EDGES + 255) / 256, 256, 0, stream>>>(ei, et, comp, xbq, xbk, aE, umax);
        edge2_kernel<<<(E_EDGES + 255) / 256, 256, 0, stream>>>(ei, aE, umax, eaE, ssum);
        msg_kernel<<<E_EDGES / 2, 256, 0, stream>>>(ei, et, comp, xb, eaE, ssum, hout);
    };

    layer(x,  IN_CH, KP1, 0, comp1, basis1, q1, k1, b1, h1);
    layer(h1, HID,   KP2, 1, comp2, basis2, q2, k2, b2, h2);
    head_kernel<<<1, 128, 0, stream>>>(h2, qidx, Wl, bl, out);
}

// Round 3
// 595.008 us; speedup vs baseline: 1.5169x; 1.1464x over previous
//
#include <hip/hip_runtime.h>
#include <math.h>

#define N_NODES 20000
#define E_EDGES 320000
#define IN_CH   300
#define HID     100
#define R_REL   50
#define NB      8
#define CLS     3
#define NQ      64
#define OUTW    800   // NB * HID
#define SCAN_BLKS ((N_NODES + 255) / 256)   // 79

typedef unsigned short ushort_t;
typedef __attribute__((ext_vector_type(8))) short     short8;
typedef __attribute__((ext_vector_type(8))) unsigned short ushort8;
typedef __attribute__((ext_vector_type(4))) float     f32x4;
typedef __attribute__((ext_vector_type(2))) float     f32x2;

__device__ __forceinline__ void split_f32(float v, ushort_t& hi, ushort_t& lo) {
    unsigned vb = __float_as_uint(v);
    hi = (ushort_t)(vb >> 16);                       // truncate to bf16
    float vh = __uint_as_float((unsigned)hi << 16);
    float l  = v - vh;                               // exact
    lo = (ushort_t)(__float_as_uint(l) >> 16);
}

// ============================ CSR build =================================
__global__ __launch_bounds__(256) void zero_deg(int* __restrict__ deg) {
    int i = blockIdx.x * 256 + threadIdx.x;
    if (i < N_NODES) deg[i] = 0;
}

__global__ __launch_bounds__(256) void hist_kernel(
        const int* __restrict__ ei, int* __restrict__ deg) {
    int e = blockIdx.x * 256 + threadIdx.x;
    if (e < E_EDGES) atomicAdd(&deg[ei[E_EDGES + e]], 1);
}

__global__ __launch_bounds__(256) void scan1_kernel(
        const int* __restrict__ deg, int* __restrict__ rowptr,
        int* __restrict__ bsum) {
    __shared__ int s[256];
    int tid = threadIdx.x;
    int idx = blockIdx.x * 256 + tid;
    int v = (idx < N_NODES) ? deg[idx] : 0;
    s[tid] = v; __syncthreads();
    #pragma unroll
    for (int off = 1; off < 256; off <<= 1) {
        int t = (tid >= off) ? s[tid - off] : 0;
        __syncthreads();
        s[tid] += t;
        __syncthreads();
    }
    if (idx < N_NODES) rowptr[idx] = s[tid] - v;   // exclusive
    if (tid == 255) bsum[blockIdx.x] = s[255];
}

__global__ __launch_bounds__(128) void scan2_kernel(int* __restrict__ bsum,
                                                    int* __restrict__ rowptr) {
    __shared__ int s[128];
    int tid = threadIdx.x;
    int v = (tid < SCAN_BLKS) ? bsum[tid] : 0;
    s[tid] = v; __syncthreads();
    #pragma unroll
    for (int off = 1; off < 128; off <<= 1) {
        int t = (tid >= off) ? s[tid - off] : 0;
        __syncthreads();
        s[tid] += t;
        __syncthreads();
    }
    if (tid < SCAN_BLKS) bsum[tid] = s[tid] - v;   // exclusive
    if (tid == 0) rowptr[N_NODES] = E_EDGES;
}

__global__ __launch_bounds__(256) void scan3_kernel(
        int* __restrict__ rowptr, const int* __restrict__ bsum,
        int* __restrict__ cursor) {
    int idx = blockIdx.x * 256 + threadIdx.x;
    if (idx < N_NODES) {
        int v = rowptr[idx] + bsum[blockIdx.x];
        rowptr[idx] = v;
        cursor[idx] = v;
    }
}

// pack (src<<6)|rel per edge into CSR position
__global__ __launch_bounds__(256) void scatter_kernel(
        const int* __restrict__ ei, const int* __restrict__ et,
        int* __restrict__ cursor, int* __restrict__ skey) {
    int e = blockIdx.x * 256 + threadIdx.x;
    if (e >= E_EDGES) return;
    int d = ei[E_EDGES + e];
    int pos = atomicAdd(&cursor[d], 1);
    skey[pos] = (ei[e] << 6) | et[e];
}

// ===================== split / transpose for MFMA GEMM ====================
__global__ __launch_bounds__(256) void split_a_kernel(
        const float* __restrict__ A, ushort_t* __restrict__ Ah,
        ushort_t* __restrict__ Al, int M, int K, int Kp, int do_relu) {
    int idx = blockIdx.x * 256 + threadIdx.x;
    if (idx >= M * Kp) return;
    int m = idx / Kp, k = idx - m * Kp;
    float v = 0.f;
    if (k < K) {
        v = A[(size_t)m * K + k];
        if (do_relu) v = fmaxf(v, 0.f);
    }
    ushort_t hi, lo;
    split_f32(v, hi, lo);
    Ah[idx] = hi; Al[idx] = lo;
}

__global__ __launch_bounds__(256) void split_bt_kernel(
        const float* __restrict__ basis, ushort_t* __restrict__ Bth,
        ushort_t* __restrict__ Btl, int K, int Kp) {
    int idx = blockIdx.x * 256 + threadIdx.x;   // n*Kp + k
    if (idx >= OUTW * Kp) return;
    int n = idx / Kp, k = idx - n * Kp;
    int b = n / HID, o = n - b * HID;
    float v = 0.f;
    if (k < K) v = basis[((size_t)b * K + k) * HID + o];
    ushort_t hi, lo;
    split_f32(v, hi, lo);
    Bth[idx] = hi; Btl[idx] = lo;
}

// ---- MFMA GEMM: C[M,800] = A[M,Kp] * B[Kp,800], split-bf16 fp32-accurate ----
// BM=128, BN=160; 4 waves in 2x2 grid, each wave 64 rows x 80 cols.
#define BM 128
#define BN 160
__global__ __launch_bounds__(256) void gemm_mfma(
        const ushort_t* __restrict__ Ah, const ushort_t* __restrict__ Al,
        const ushort_t* __restrict__ Bth, const ushort_t* __restrict__ Btl,
        float* __restrict__ C, int M, int Kp) {
    __shared__ ushort_t As_h[BM][40], As_l[BM][40];
    __shared__ ushort_t Bs_h[BN][40], Bs_l[BN][40];
    int tid  = threadIdx.x;
    int lane = tid & 63, wave = tid >> 6;
    int ml = lane & 15, quad = lane >> 4;
    int wr = (wave >> 1) * 64, wc = (wave & 1) * 80;
    int row0 = blockIdx.y * BM, col0 = blockIdx.x * BN;
    f32x4 acc[4][5] = {};
    int ksteps = Kp >> 5;
    for (int ks = 0; ks < ksteps; ks++) {
        int k0 = ks << 5;
        __syncthreads();
        // stage A: 128 rows x 4 chunks of 16B
        #pragma unroll
        for (int p = 0; p < 2; p++) {
            int ra = p * 64 + (tid >> 2), ch = tid & 3;
            int gr = row0 + ra;
            ushort8 vh = {0,0,0,0,0,0,0,0}, vl = {0,0,0,0,0,0,0,0};
            if (gr < M) {
                vh = *(const ushort8*)&Ah[(size_t)gr * Kp + k0 + ch * 8];
                vl = *(const ushort8*)&Al[(size_t)gr * Kp + k0 + ch * 8];
            }
            *(ushort8*)&As_h[ra][ch * 8] = vh;
            *(ushort8*)&As_l[ra][ch * 8] = vl;
        }
        // stage B: 160 rows x 4 chunks = 640 tasks
        for (int t = tid; t < 640; t += 256) {
            int rb = t >> 2, ch = t & 3;
            ushort8 vh = *(const ushort8*)&Bth[(size_t)(col0 + rb) * Kp + k0 + ch * 8];
            ushort8 vl = *(const ushort8*)&Btl[(size_t)(col0 + rb) * Kp + k0 + ch * 8];
            *(ushort8*)&Bs_h[rb][ch * 8] = vh;
            *(ushort8*)&Bs_l[rb][ch * 8] = vl;
        }
        __syncthreads();
        short8 ah[4], al[4], bh[5], bl5[5];
        #pragma unroll
        for (int mt = 0; mt < 4; mt++) {
            int r = wr + mt * 16 + ml;
            ah[mt] = *(const short8*)&As_h[r][quad * 8];
            al[mt] = *(const short8*)&As_l[r][quad * 8];
        }
        #pragma unroll
        for (int nt = 0; nt < 5; nt++) {
            int r = wc + nt * 16 + ml;
            bh[nt]  = *(const short8*)&Bs_h[r][quad * 8];
            bl5[nt] = *(const short8*)&Bs_l[r][quad * 8];
        }
        #pragma unroll
        for (int mt = 0; mt < 4; mt++)
            #pragma unroll
            for (int nt = 0; nt < 5; nt++) {
                acc[mt][nt] = __builtin_amdgcn_mfma_f32_16x16x32_bf16(ah[mt], bh[nt],  acc[mt][nt], 0, 0, 0);
                acc[mt][nt] = __builtin_amdgcn_mfma_f32_16x16x32_bf16(al[mt], bh[nt],  acc[mt][nt], 0, 0, 0);
                acc[mt][nt] = __builtin_amdgcn_mfma_f32_16x16x32_bf16(ah[mt], bl5[nt], acc[mt][nt], 0, 0, 0);
            }
    }
    // epilogue: C/D layout col = lane&15, row = quad*4 + reg
    #pragma unroll
    for (int mt = 0; mt < 4; mt++) {
        #pragma unroll
        for (int nt = 0; nt < 5; nt++) {
            #pragma unroll
            for (int r = 0; r < 4; r++) {
                int grow = row0 + wr + mt * 16 + quad * 4 + r;
                if (grow < M)
                    C[(size_t)grow * OUTW + col0 + wc + nt * 16 + ml] = acc[mt][nt][r];
            }
        }
    }
}

// ---- xbq[n,b] = xb[n,b,:] . q ; xbk likewise ----
__global__ __launch_bounds__(256) void qk_kernel(
        const float* __restrict__ xb, const float* __restrict__ q,
        const float* __restrict__ k, float* __restrict__ xbq,
        float* __restrict__ xbk) {
    __shared__ float sq[HID], sk[HID];
    int tid = threadIdx.x;
    if (tid < HID) { sq[tid] = q[tid]; sk[tid] = k[tid]; }
    __syncthreads();
    int idx = blockIdx.x * 256 + tid;   // idx = n*NB + b
    if (idx >= N_NODES * NB) return;
    const float* base = xb + (size_t)idx * HID;
    float aq = 0.f, ak = 0.f;
    #pragma unroll 4
    for (int o = 0; o < HID; o++) {
        float v = base[o];
        aq = fmaf(v, sq[o], aq);
        ak = fmaf(v, sk[o], ak);
    }
    xbq[idx] = aq;
    xbk[idx] = ak;
}

// ==== fused per-dst: attention logits + online softmax + message + bias ====
// one wave per dst node; lanes = edges in pass 1, channel pairs in pass 2
__global__ __launch_bounds__(256) void msg_csr(
        const int* __restrict__ rowptr, const int* __restrict__ skey,
        const float* __restrict__ comp, const float* __restrict__ xb,
        const float* __restrict__ xbq, const float* __restrict__ xbk,
        const float* __restrict__ bias, float* __restrict__ h) {
    int wave = threadIdx.x >> 6, lane = threadIdx.x & 63;
    int d = blockIdx.x * 4 + wave;
    if (d >= N_NODES) return;
    int beg = rowptr[d], end = rowptr[d + 1];

    // preload xbq[d, 0..8] (wave-uniform broadcast loads)
    float4 qd0 = *(const float4*)&xbq[d * NB];
    float4 qd1 = *(const float4*)&xbq[d * NB + 4];

    f32x2 acc = {0.f, 0.f};
    float m = -1e30f, l = 0.f;
    int o = lane * 2;                 // channel pair for pass 2

    for (int c0 = beg; c0 < end; c0 += 64) {
        int p = c0 + lane;
        bool valid = p < end;
        int s = 0, rt = 0;
        float a = -1e30f;
        if (valid) {
            int key = skey[p];
            s = key >> 6; rt = key & 63;
            const float4 c0v = *(const float4*)&comp[rt * NB];
            const float4 c1v = *(const float4*)&comp[rt * NB + 4];
            const float4 k0v = *(const float4*)&xbk[s * NB];
            const float4 k1v = *(const float4*)&xbk[s * NB + 4];
            float qi = c0v.x*qd0.x + c0v.y*qd0.y + c0v.z*qd0.z + c0v.w*qd0.w
                     + c1v.x*qd1.x + c1v.y*qd1.y + c1v.z*qd1.z + c1v.w*qd1.w;
            float kj = c0v.x*k0v.x + c0v.y*k0v.y + c0v.z*k0v.z + c0v.w*k0v.w
                     + c1v.x*k1v.x + c1v.y*k1v.y + c1v.z*k1v.z + c1v.w*k1v.w;
            a = qi + kj;
            a = a > 0.f ? a : 0.2f * a;     // leaky_relu 0.2
        }
        // wave max reduce
        float cm = a;
        #pragma unroll
        for (int off = 32; off; off >>= 1) cm = fmaxf(cm, __shfl_xor(cm, off));
        float M = fmaxf(m, cm);
        // rescale running accumulator
        float scale = __expf(m - M);
        acc *= scale; l *= scale; m = M;
        float wgt = valid ? __expf(a - M) : 0.f;
        float cs = wgt;
        #pragma unroll
        for (int off = 32; off; off >>= 1) cs += __shfl_xor(cs, off);
        l += cs;
        int cnt = end - c0; if (cnt > 64) cnt = 64;
        for (int j = 0; j < cnt; j++) {
            float wj = __shfl(wgt, j);
            int   sj = __shfl(s, j);
            int   rj = __shfl(rt, j);
            if (lane < 50) {
                const float* cr = comp + rj * NB;
                const float* xs = xb + (size_t)sj * OUTW + o;
                f32x2 t = {0.f, 0.f};
                #pragma unroll
                for (int b = 0; b < NB; b++)
                    t += cr[b] * (*(const f32x2*)&xs[b * HID]);
                acc += wj * t;
            }
        }
    }
    if (lane < 50) {
        float inv = 1.f / (l + 1e-16f);
        f32x2 r;
        r.x = bias[o]     + acc.x * inv;
        r.y = bias[o + 1] + acc.y * inv;
        *(f32x2*)&h[(size_t)d * HID + o] = r;
    }
}

// ---- pooled = mean(relu(h2[qidx])); out = pooled @ Wl^T + bl ----
__global__ __launch_bounds__(128) void head_kernel(
        const float* __restrict__ h2, const int* __restrict__ qidx,
        const float* __restrict__ Wl, const float* __restrict__ bl,
        float* __restrict__ out) {
    __shared__ float pooled[HID];
    int tid = threadIdx.x;
    if (tid < HID) {
        float s = 0.f;
        for (int i = 0; i < NQ; i++)
            s += fmaxf(h2[(size_t)qidx[i] * HID + tid], 0.f);
        pooled[tid] = s * (1.0f / NQ);
    }
    __syncthreads();
    if (tid < CLS) {
        float s = bl[tid];
        for (int o = 0; o < HID; o++) s = fmaf(pooled[o], Wl[tid * HID + o], s);
        out[tid] = s;
    }
}

extern "C" void kernel_launch(void* const* d_in, const int* in_sizes, int n_in,
                              void* d_out, int out_size, void* d_ws, size_t ws_size,
                              hipStream_t stream) {
    const float* x      = (const float*)d_in[0];
    const int*   ei     = (const int*)  d_in[1];
    const int*   et     = (const int*)  d_in[2];
    const int*   qidx   = (const int*)  d_in[3];
    const float* comp1  = (const float*)d_in[4];
    const float* basis1 = (const float*)d_in[5];
    const float* q1     = (const float*)d_in[6];
    const float* k1     = (const float*)d_in[7];
    const float* b1     = (const float*)d_in[8];
    const float* comp2  = (const float*)d_in[9];
    const float* basis2 = (const float*)d_in[10];
    const float* q2     = (const float*)d_in[11];
    const float* k2     = (const float*)d_in[12];
    const float* b2     = (const float*)d_in[13];
    const float* Wl     = (const float*)d_in[14];
    const float* bl     = (const float*)d_in[15];
    float* out = (float*)d_out;

    const int KP1 = 320, KP2 = 128;

    char* w = (char*)d_ws;
    size_t off = 0;
    auto alloc = [&](size_t nbytes) {
        void* p = (void*)(w + off);
        off += ((nbytes + 255) / 256) * 256;
        return p;
    };
    float*    xb     = (float*)alloc((size_t)N_NODES * OUTW * 4);   // 64 MB
    float*    h1     = (float*)alloc((size_t)N_NODES * HID * 4);    // 8 MB
    float*    h2     = (float*)alloc((size_t)N_NODES * HID * 4);    // 8 MB
    ushort_t* Ah     = (ushort_t*)alloc((size_t)N_NODES * KP1 * 2); // 12.8 MB
    ushort_t* Al     = (ushort_t*)alloc((size_t)N_NODES * KP1 * 2); // 12.8 MB
    ushort_t* Bth    = (ushort_t*)alloc((size_t)OUTW * KP1 * 2);
    ushort_t* Btl    = (ushort_t*)alloc((size_t)OUTW * KP1 * 2);
    float*    xbq    = (float*)alloc((size_t)N_NODES * NB * 4);
    float*    xbk    = (float*)alloc((size_t)N_NODES * NB * 4);
    int*      deg    = (int*)alloc(N_NODES * 4);
    int*      rowptr = (int*)alloc((N_NODES + 1) * 4);
    int*      cursor = (int*)alloc(N_NODES * 4);
    int*      bsum   = (int*)alloc(SCAN_BLKS * 4);
    int*      skey   = (int*)alloc(E_EDGES * 4);

    // ---- CSR build (once; same graph both layers) ----
    zero_deg<<<SCAN_BLKS, 256, 0, stream>>>(deg);
    hist_kernel<<<(E_EDGES + 255) / 256, 256, 0, stream>>>(ei, deg);
    scan1_kernel<<<SCAN_BLKS, 256, 0, stream>>>(deg, rowptr, bsum);
    scan2_kernel<<<1, 128, 0, stream>>>(bsum, rowptr);
    scan3_kernel<<<SCAN_BLKS, 256, 0, stream>>>(rowptr, bsum, cursor);
    scatter_kernel<<<(E_EDGES + 255) / 256, 256, 0, stream>>>(ei, et, cursor, skey);

    auto layer = [&](const float* input, int K, int Kp, int relu_in,
                     const float* comp, const float* basis, const float* q,
                     const float* k, const float* bias, float* hout) {
        int na = N_NODES * Kp;
        split_a_kernel<<<(na + 255) / 256, 256, 0, stream>>>(input, Ah, Al, N_NODES, K, Kp, relu_in);
        int nb = OUTW * Kp;
        split_bt_kernel<<<(nb + 255) / 256, 256, 0, stream>>>(basis, Bth, Btl, K, Kp);
        dim3 g(OUTW / BN, (N_NODES + BM - 1) / BM);
        gemm_mfma<<<g, 256, 0, stream>>>(Ah, Al, Bth, Btl, xb, N_NODES, Kp);
        qk_kernel<<<(N_NODES * NB + 255) / 256, 256, 0, stream>>>(xb, q, k, xbq, xbk);
        msg_csr<<<(N_NODES + 3) / 4, 256, 0, stream>>>(rowptr, skey, comp, xb, xbq, xbk, bias, hout);
    };

    layer(x,  IN_CH, KP1, 0, comp1, basis1, q1, k1, b1, h1);
    layer(h1, HID,   KP2, 1, comp2, basis2, q2, k2, b2, h2);
    head_kernel<<<1, 128, 0, stream>>>(h2, qidx, Wl, bl, out);
}

// Round 4
// 487.510 us; speedup vs baseline: 1.8514x; 1.2205x over previous
//
#include <hip/hip_runtime.h>
#include <math.h>

#define N_NODES 20000
#define E_EDGES 320000
#define IN_CH   300
#define HID     100
#define R_REL   50
#define NB      8
#define CLS     3
#define NQ      64
#define OUTW    800   // NB * HID
#define SCAN_BLKS ((N_NODES + 255) / 256)   // 79

typedef unsigned short ushort_t;
typedef __attribute__((ext_vector_type(8))) short     short8;
typedef __attribute__((ext_vector_type(8))) unsigned short ushort8;
typedef __attribute__((ext_vector_type(4))) float     f32x4;
typedef __attribute__((ext_vector_type(2))) float     f32x2;

__device__ __forceinline__ void split_f32(float v, ushort_t& hi, ushort_t& lo) {
    unsigned vb = __float_as_uint(v);
    hi = (ushort_t)(vb >> 16);                       // truncate to bf16
    float vh = __uint_as_float((unsigned)hi << 16);
    float l  = v - vh;                               // exact
    lo = (ushort_t)(__float_as_uint(l) >> 16);
}

__device__ __forceinline__ ushort_t f2bf_rne(float f) {   // round-nearest-even
    unsigned u = __float_as_uint(f);
    unsigned r = (u + 0x7fffu + ((u >> 16) & 1u)) >> 16;
    return (ushort_t)r;
}
__device__ __forceinline__ float bf2f(ushort_t u) {
    return __uint_as_float((unsigned)u << 16);
}

// ============================ CSR build =================================
__global__ __launch_bounds__(256) void zero_deg2(int* __restrict__ dd,
                                                 int* __restrict__ ds) {
    int i = blockIdx.x * 256 + threadIdx.x;
    if (i < N_NODES) { dd[i] = 0; ds[i] = 0; }
}

__global__ __launch_bounds__(256) void hist2_kernel(
        const int* __restrict__ ei, int* __restrict__ dd,
        int* __restrict__ ds) {
    int e = blockIdx.x * 256 + threadIdx.x;
    if (e < E_EDGES) {
        atomicAdd(&dd[ei[E_EDGES + e]], 1);
        atomicAdd(&ds[ei[e]], 1);
    }
}

__global__ __launch_bounds__(256) void scan1_kernel(
        const int* __restrict__ deg, int* __restrict__ rowptr,
        int* __restrict__ bsum) {
    __shared__ int s[256];
    int tid = threadIdx.x;
    int idx = blockIdx.x * 256 + tid;
    int v = (idx < N_NODES) ? deg[idx] : 0;
    s[tid] = v; __syncthreads();
    #pragma unroll
    for (int off = 1; off < 256; off <<= 1) {
        int t = (tid >= off) ? s[tid - off] : 0;
        __syncthreads();
        s[tid] += t;
        __syncthreads();
    }
    if (idx < N_NODES) rowptr[idx] = s[tid] - v;   // exclusive
    if (tid == 255) bsum[blockIdx.x] = s[255];
}

__global__ __launch_bounds__(128) void scan2_kernel(int* __restrict__ bsum,
                                                    int* __restrict__ rowptr) {
    __shared__ int s[128];
    int tid = threadIdx.x;
    int v = (tid < SCAN_BLKS) ? bsum[tid] : 0;
    s[tid] = v; __syncthreads();
    #pragma unroll
    for (int off = 1; off < 128; off <<= 1) {
        int t = (tid >= off) ? s[tid - off] : 0;
        __syncthreads();
        s[tid] += t;
        __syncthreads();
    }
    if (tid < SCAN_BLKS) bsum[tid] = s[tid] - v;   // exclusive
    if (tid == 0) rowptr[N_NODES] = E_EDGES;
}

__global__ __launch_bounds__(256) void scan3_kernel(
        int* __restrict__ rowptr, const int* __restrict__ bsum,
        int* __restrict__ cursor) {
    int idx = blockIdx.x * 256 + threadIdx.x;
    if (idx < N_NODES) {
        int v = rowptr[idx] + bsum[blockIdx.x];
        rowptr[idx] = v;
        cursor[idx] = v;
    }
}

// both scatters fused: dst slot p known in-thread, feeds src-CSR payload
__global__ __launch_bounds__(256) void scatter_both(
        const int* __restrict__ ei, const int* __restrict__ et,
        int* __restrict__ cur_d, int* __restrict__ cur_s,
        int* __restrict__ skey, int* __restrict__ skey_s) {
    int e = blockIdx.x * 256 + threadIdx.x;
    if (e >= E_EDGES) return;
    int s = ei[e], d = ei[E_EDGES + e], rt = et[e];
    int p = atomicAdd(&cur_d[d], 1);
    skey[p] = (s << 6) | rt;                 // dst-order: (src, rel)
    int qp = atomicAdd(&cur_s[s], 1);
    skey_s[qp] = (p << 6) | rt;              // src-order: (dst-slot, rel)
}

// ===================== split / transpose for MFMA GEMM ====================
__global__ __launch_bounds__(256) void split_a_kernel(
        const float* __restrict__ A, ushort_t* __restrict__ Ah,
        ushort_t* __restrict__ Al, int M, int K, int Kp, int do_relu) {
    int idx = blockIdx.x * 256 + threadIdx.x;
    if (idx >= M * Kp) return;
    int m = idx / Kp, k = idx - m * Kp;
    float v = 0.f;
    if (k < K) {
        v = A[(size_t)m * K + k];
        if (do_relu) v = fmaxf(v, 0.f);
    }
    ushort_t hi, lo;
    split_f32(v, hi, lo);
    Ah[idx] = hi; Al[idx] = lo;
}

__global__ __launch_bounds__(256) void split_bt_kernel(
        const float* __restrict__ basis, ushort_t* __restrict__ Bth,
        ushort_t* __restrict__ Btl, int K, int Kp) {
    int idx = blockIdx.x * 256 + threadIdx.x;   // n*Kp + k
    if (idx >= OUTW * Kp) return;
    int n = idx / Kp, k = idx - n * Kp;
    int b = n / HID, o = n - b * HID;
    float v = 0.f;
    if (k < K) v = basis[((size_t)b * K + k) * HID + o];
    ushort_t hi, lo;
    split_f32(v, hi, lo);
    Bth[idx] = hi; Btl[idx] = lo;
}

// ---- MFMA GEMM: C[M,800] = A[M,Kp] * B[Kp,800], split-bf16 fp32-accurate ----
#define BM 128
#define BN 160
__global__ __launch_bounds__(256) void gemm_mfma(
        const ushort_t* __restrict__ Ah, const ushort_t* __restrict__ Al,
        const ushort_t* __restrict__ Bth, const ushort_t* __restrict__ Btl,
        float* __restrict__ C, int M, int Kp) {
    __shared__ ushort_t As_h[BM][40], As_l[BM][40];
    __shared__ ushort_t Bs_h[BN][40], Bs_l[BN][40];
    int tid  = threadIdx.x;
    int lane = tid & 63, wave = tid >> 6;
    int ml = lane & 15, quad = lane >> 4;
    int wr = (wave >> 1) * 64, wc = (wave & 1) * 80;
    int row0 = blockIdx.y * BM, col0 = blockIdx.x * BN;
    f32x4 acc[4][5] = {};
    int ksteps = Kp >> 5;
    for (int ks = 0; ks < ksteps; ks++) {
        int k0 = ks << 5;
        __syncthreads();
        #pragma unroll
        for (int p = 0; p < 2; p++) {
            int ra = p * 64 + (tid >> 2), ch = tid & 3;
            int gr = row0 + ra;
            ushort8 vh = {0,0,0,0,0,0,0,0}, vl = {0,0,0,0,0,0,0,0};
            if (gr < M) {
                vh = *(const ushort8*)&Ah[(size_t)gr * Kp + k0 + ch * 8];
                vl = *(const ushort8*)&Al[(size_t)gr * Kp + k0 + ch * 8];
            }
            *(ushort8*)&As_h[ra][ch * 8] = vh;
            *(ushort8*)&As_l[ra][ch * 8] = vl;
        }
        for (int t = tid; t < 640; t += 256) {
            int rb = t >> 2, ch = t & 3;
            ushort8 vh = *(const ushort8*)&Bth[(size_t)(col0 + rb) * Kp + k0 + ch * 8];
            ushort8 vl = *(const ushort8*)&Btl[(size_t)(col0 + rb) * Kp + k0 + ch * 8];
            *(ushort8*)&Bs_h[rb][ch * 8] = vh;
            *(ushort8*)&Bs_l[rb][ch * 8] = vl;
        }
        __syncthreads();
        short8 ah[4], al[4], bh[5], bl5[5];
        #pragma unroll
        for (int mt = 0; mt < 4; mt++) {
            int r = wr + mt * 16 + ml;
            ah[mt] = *(const short8*)&As_h[r][quad * 8];
            al[mt] = *(const short8*)&As_l[r][quad * 8];
        }
        #pragma unroll
        for (int nt = 0; nt < 5; nt++) {
            int r = wc + nt * 16 + ml;
            bh[nt]  = *(const short8*)&Bs_h[r][quad * 8];
            bl5[nt] = *(const short8*)&Bs_l[r][quad * 8];
        }
        #pragma unroll
        for (int mt = 0; mt < 4; mt++)
            #pragma unroll
            for (int nt = 0; nt < 5; nt++) {
                acc[mt][nt] = __builtin_amdgcn_mfma_f32_16x16x32_bf16(ah[mt], bh[nt],  acc[mt][nt], 0, 0, 0);
                acc[mt][nt] = __builtin_amdgcn_mfma_f32_16x16x32_bf16(al[mt], bh[nt],  acc[mt][nt], 0, 0, 0);
                acc[mt][nt] = __builtin_amdgcn_mfma_f32_16x16x32_bf16(ah[mt], bl5[nt], acc[mt][nt], 0, 0, 0);
            }
    }
    #pragma unroll
    for (int mt = 0; mt < 4; mt++) {
        #pragma unroll
        for (int nt = 0; nt < 5; nt++) {
            #pragma unroll
            for (int r = 0; r < 4; r++) {
                int grow = row0 + wr + mt * 16 + quad * 4 + r;
                if (grow < M)
                    C[(size_t)grow * OUTW + col0 + wc + nt * 16 + ml] = acc[mt][nt][r];
            }
        }
    }
}

// ---- qb[k*8+b] = sum_o basis[b,k,o]*q[o]; kb likewise ----
__global__ __launch_bounds__(256) void qbkb_kernel(
        const float* __restrict__ basis, const float* __restrict__ q,
        const float* __restrict__ k, float* __restrict__ qb,
        float* __restrict__ kb, int K) {
    int idx = blockIdx.x * 256 + threadIdx.x;
    if (idx >= K * NB) return;
    int kk = idx >> 3, b = idx & 7;
    const float* br = basis + ((size_t)b * K + kk) * HID;
    float aq = 0.f, ak = 0.f;
    for (int o = 0; o < HID; o++) {
        float v = br[o];
        aq = fmaf(v, q[o], aq);
        ak = fmaf(v, k[o], ak);
    }
    qb[idx] = aq; kb[idx] = ak;
}

// ---- xbq[n,b] = sum_k in[n,k]*qb[k,b] (reads input, not xb) ----
__global__ __launch_bounds__(256) void qk2_kernel(
        const float* __restrict__ x, const float* __restrict__ qb,
        const float* __restrict__ kb, float* __restrict__ xbq,
        float* __restrict__ xbk, int K, int do_relu) {
    __shared__ float sqb[320 * NB], skb[320 * NB];
    int tid = threadIdx.x;
    for (int i = tid; i < K * NB; i += 256) { sqb[i] = qb[i]; skb[i] = kb[i]; }
    __syncthreads();
    int idx = blockIdx.x * 256 + tid;     // n*8 + b
    if (idx >= N_NODES * NB) return;
    int n = idx >> 3, b = idx & 7;
    const float* xr = x + (size_t)n * K;
    float aq = 0.f, ak = 0.f;
    for (int kk = 0; kk < K; kk++) {
        float v = xr[kk];
        if (do_relu) v = fmaxf(v, 0.f);
        aq = fmaf(v, sqb[kk * NB + b], aq);
        ak = fmaf(v, skb[kk * NB + b], ak);
    }
    xbq[idx] = aq;
    xbk[idx] = ak;
}

// ==== src-major: Z[dstslot,:] = sum_b comp[rt,b]*xb[s,b,:]  (bf16 out) ====
__global__ __launch_bounds__(256) void compute_z(
        const int* __restrict__ rowptr_s, const int* __restrict__ skey_s,
        const float* __restrict__ comp, const float* __restrict__ xb,
        ushort_t* __restrict__ Z) {
    int wave = threadIdx.x >> 6, lane = threadIdx.x & 63;
    int s = blockIdx.x * 4 + wave;
    if (s >= N_NODES) return;
    int beg = rowptr_s[s], end = rowptr_s[s + 1];
    if (beg == end) return;
    int o = lane * 2;
    f32x2 xrow[NB];
    if (lane < 50) {
        #pragma unroll
        for (int b = 0; b < NB; b++)
            xrow[b] = *(const f32x2*)&xb[(size_t)s * OUTW + b * HID + o];
    }
    for (int p = beg; p < end; p++) {
        int key = skey_s[p];
        int zpos = key >> 6, rt = key & 63;
        const float* cr = comp + rt * NB;
        if (lane < 50) {
            f32x2 z = {0.f, 0.f};
            #pragma unroll
            for (int b = 0; b < NB; b++) z += cr[b] * xrow[b];
            ushort2 zz;
            zz.x = f2bf_rne(z.x);
            zz.y = f2bf_rne(z.y);
            *(ushort2*)&Z[(size_t)zpos * HID + o] = zz;
        }
    }
}

// ==== dst-major: online softmax + streaming Z accumulation + bias ====
__global__ __launch_bounds__(256) void msg_soft(
        const int* __restrict__ rowptr, const int* __restrict__ skey,
        const float* __restrict__ comp, const ushort_t* __restrict__ Z,
        const float* __restrict__ xbq, const float* __restrict__ xbk,
        const float* __restrict__ bias, float* __restrict__ h) {
    int wave = threadIdx.x >> 6, lane = threadIdx.x & 63;
    int d = blockIdx.x * 4 + wave;
    if (d >= N_NODES) return;
    int beg = rowptr[d], end = rowptr[d + 1];

    float4 qd0 = *(const float4*)&xbq[d * NB];
    float4 qd1 = *(const float4*)&xbq[d * NB + 4];

    f32x2 acc = {0.f, 0.f};
    float m = -1e30f, l = 0.f;
    int o = lane * 2;

    for (int c0 = beg; c0 < end; c0 += 64) {
        int p = c0 + lane;
        bool valid = p < end;
        float a = -1e30f;
        if (valid) {
            int key = skey[p];
            int s = key >> 6, rt = key & 63;
            const float4 c0v = *(const float4*)&comp[rt * NB];
            const float4 c1v = *(const float4*)&comp[rt * NB + 4];
            const float4 k0v = *(const float4*)&xbk[s * NB];
            const float4 k1v = *(const float4*)&xbk[s * NB + 4];
            float qi = c0v.x*qd0.x + c0v.y*qd0.y + c0v.z*qd0.z + c0v.w*qd0.w
                     + c1v.x*qd1.x + c1v.y*qd1.y + c1v.z*qd1.z + c1v.w*qd1.w;
            float kj = c0v.x*k0v.x + c0v.y*k0v.y + c0v.z*k0v.z + c0v.w*k0v.w
                     + c1v.x*k1v.x + c1v.y*k1v.y + c1v.z*k1v.z + c1v.w*k1v.w;
            a = qi + kj;
            a = a > 0.f ? a : 0.2f * a;     // leaky_relu 0.2
        }
        float cm = a;
        #pragma unroll
        for (int off = 32; off; off >>= 1) cm = fmaxf(cm, __shfl_xor(cm, off));
        float M = fmaxf(m, cm);
        float scale = __expf(m - M);
        acc *= scale; l *= scale; m = M;
        float wgt = valid ? __expf(a - M) : 0.f;
        float cs = wgt;
        #pragma unroll
        for (int off = 32; off; off >>= 1) cs += __shfl_xor(cs, off);
        l += cs;
        int cnt = end - c0; if (cnt > 64) cnt = 64;
        for (int j = 0; j < cnt; j++) {
            float wj = __shfl(wgt, j);
            if (lane < 50) {
                ushort2 zz = *(const ushort2*)&Z[(size_t)(c0 + j) * HID + o];
                f32x2 zv = {bf2f(zz.x), bf2f(zz.y)};
                acc += wj * zv;
            }
        }
    }
    if (lane < 50) {
        float inv = 1.f / (l + 1e-16f);
        f32x2 r;
        r.x = bias[o]     + acc.x * inv;
        r.y = bias[o + 1] + acc.y * inv;
        *(f32x2*)&h[(size_t)d * HID + o] = r;
    }
}

// ---- pooled = mean(relu(h2[qidx])); out = pooled @ Wl^T + bl ----
__global__ __launch_bounds__(128) void head_kernel(
        const float* __restrict__ h2, const int* __restrict__ qidx,
        const float* __restrict__ Wl, const float* __restrict__ bl,
        float* __restrict__ out) {
    __shared__ float pooled[HID];
    int tid = threadIdx.x;
    if (tid < HID) {
        float s = 0.f;
        for (int i = 0; i < NQ; i++)
            s += fmaxf(h2[(size_t)qidx[i] * HID + tid], 0.f);
        pooled[tid] = s * (1.0f / NQ);
    }
    __syncthreads();
    if (tid < CLS) {
        float s = bl[tid];
        for (int o = 0; o < HID; o++) s = fmaf(pooled[o], Wl[tid * HID + o], s);
        out[tid] = s;
    }
}

extern "C" void kernel_launch(void* const* d_in, const int* in_sizes, int n_in,
                              void* d_out, int out_size, void* d_ws, size_t ws_size,
                              hipStream_t stream) {
    const float* x      = (const float*)d_in[0];
    const int*   ei     = (const int*)  d_in[1];
    const int*   et     = (const int*)  d_in[2];
    const int*   qidx   = (const int*)  d_in[3];
    const float* comp1  = (const float*)d_in[4];
    const float* basis1 = (const float*)d_in[5];
    const float* q1     = (const float*)d_in[6];
    const float* k1     = (const float*)d_in[7];
    const float* b1     = (const float*)d_in[8];
    const float* comp2  = (const float*)d_in[9];
    const float* basis2 = (const float*)d_in[10];
    const float* q2     = (const float*)d_in[11];
    const float* k2     = (const float*)d_in[12];
    const float* b2     = (const float*)d_in[13];
    const float* Wl     = (const float*)d_in[14];
    const float* bl     = (const float*)d_in[15];
    float* out = (float*)d_out;

    const int KP1 = 320, KP2 = 128;

    char* w = (char*)d_ws;
    size_t off = 0;
    auto alloc = [&](size_t nbytes) {
        void* p = (void*)(w + off);
        off += ((nbytes + 255) / 256) * 256;
        return p;
    };
    float*    xb     = (float*)alloc((size_t)N_NODES * OUTW * 4);   // 64 MB
    ushort_t* Z      = (ushort_t*)alloc((size_t)E_EDGES * HID * 2); // 64 MB
    float*    h1     = (float*)alloc((size_t)N_NODES * HID * 4);    // 8 MB
    float*    h2     = (float*)alloc((size_t)N_NODES * HID * 4);    // 8 MB
    ushort_t* Ah     = (ushort_t*)alloc((size_t)N_NODES * KP1 * 2); // 12.8 MB
    ushort_t* Al     = (ushort_t*)alloc((size_t)N_NODES * KP1 * 2); // 12.8 MB
    ushort_t* Bth    = (ushort_t*)alloc((size_t)OUTW * KP1 * 2);
    ushort_t* Btl    = (ushort_t*)alloc((size_t)OUTW * KP1 * 2);
    float*    xbq    = (float*)alloc((size_t)N_NODES * NB * 4);
    float*    xbk    = (float*)alloc((size_t)N_NODES * NB * 4);
    float*    qb     = (float*)alloc((size_t)KP1 * NB * 4);
    float*    kb     = (float*)alloc((size_t)KP1 * NB * 4);
    int*      deg_d  = (int*)alloc(N_NODES * 4);
    int*      deg_s  = (int*)alloc(N_NODES * 4);
    int*      rp_d   = (int*)alloc((N_NODES + 1) * 4);
    int*      rp_s   = (int*)alloc((N_NODES + 1) * 4);
    int*      cur_d  = (int*)alloc(N_NODES * 4);
    int*      cur_s  = (int*)alloc(N_NODES * 4);
    int*      bsum   = (int*)alloc(SCAN_BLKS * 4);
    int*      skey   = (int*)alloc(E_EDGES * 4);
    int*      skey_s = (int*)alloc(E_EDGES * 4);

    // ---- CSR build (once; same graph both layers) ----
    zero_deg2<<<SCAN_BLKS, 256, 0, stream>>>(deg_d, deg_s);
    hist2_kernel<<<(E_EDGES + 255) / 256, 256, 0, stream>>>(ei, deg_d, deg_s);
    scan1_kernel<<<SCAN_BLKS, 256, 0, stream>>>(deg_d, rp_d, bsum);
    scan2_kernel<<<1, 128, 0, stream>>>(bsum, rp_d);
    scan3_kernel<<<SCAN_BLKS, 256, 0, stream>>>(rp_d, bsum, cur_d);
    scan1_kernel<<<SCAN_BLKS, 256, 0, stream>>>(deg_s, rp_s, bsum);
    scan2_kernel<<<1, 128, 0, stream>>>(bsum, rp_s);
    scan3_kernel<<<SCAN_BLKS, 256, 0, stream>>>(rp_s, bsum, cur_s);
    scatter_both<<<(E_EDGES + 255) / 256, 256, 0, stream>>>(ei, et, cur_d, cur_s, skey, skey_s);

    auto layer = [&](const float* input, int K, int Kp, int relu_in,
                     const float* comp, const float* basis, const float* q,
                     const float* k, const float* bias, float* hout) {
        int na = N_NODES * Kp;
        split_a_kernel<<<(na + 255) / 256, 256, 0, stream>>>(input, Ah, Al, N_NODES, K, Kp, relu_in);
        int nb = OUTW * Kp;
        split_bt_kernel<<<(nb + 255) / 256, 256, 0, stream>>>(basis, Bth, Btl, K, Kp);
        dim3 g(OUTW / BN, (N_NODES + BM - 1) / BM);
        gemm_mfma<<<g, 256, 0, stream>>>(Ah, Al, Bth, Btl, xb, N_NODES, Kp);
        qbkb_kernel<<<(K * NB + 255) / 256, 256, 0, stream>>>(basis, q, k, qb, kb, K);
        qk2_kernel<<<(N_NODES * NB + 255) / 256, 256, 0, stream>>>(input, qb, kb, xbq, xbk, K, relu_in);
        compute_z<<<(N_NODES + 3) / 4, 256, 0, stream>>>(rp_s, skey_s, comp, xb, Z);
        msg_soft<<<(N_NODES + 3) / 4, 256, 0, stream>>>(rp_d, skey, comp, Z, xbq, xbk, bias, hout);
    };

    layer(x,  IN_CH, KP1, 0, comp1, basis1, q1, k1, b1, h1);
    layer(h1, HID,   KP2, 1, comp2, basis2, q2, k2, b2, h2);
    head_kernel<<<1, 128, 0, stream>>>(h2, qidx, Wl, bl, out);
}

// Round 5
// 478.450 us; speedup vs baseline: 1.8865x; 1.0189x over previous
//
#include <hip/hip_runtime.h>
#include <math.h>

#define N_NODES 20000
#define E_EDGES 320000
#define IN_CH   300
#define HID     100
#define R_REL   50
#define NB      8
#define CLS     3
#define NQ      64
#define OUTW    800   // NB * HID
#define SCAN_BLKS ((N_NODES + 255) / 256)   // 79

typedef unsigned short ushort_t;
typedef __attribute__((ext_vector_type(8))) short     short8;
typedef __attribute__((ext_vector_type(8))) unsigned short ushort8;
typedef __attribute__((ext_vector_type(4))) float     f32x4;
typedef __attribute__((ext_vector_type(2))) float     f32x2;

__device__ __forceinline__ void split_f32(float v, ushort_t& hi, ushort_t& lo) {
    unsigned vb = __float_as_uint(v);
    hi = (ushort_t)(vb >> 16);                       // truncate to bf16
    float vh = __uint_as_float((unsigned)hi << 16);
    float l  = v - vh;                               // exact
    lo = (ushort_t)(__float_as_uint(l) >> 16);
}

__device__ __forceinline__ ushort_t f2bf_rne(float f) {   // round-nearest-even
    unsigned u = __float_as_uint(f);
    unsigned r = (u + 0x7fffu + ((u >> 16) & 1u)) >> 16;
    return (ushort_t)r;
}
__device__ __forceinline__ float bf2f(ushort_t u) {
    return __uint_as_float((unsigned)u << 16);
}

// ============================ CSR build =================================
__global__ __launch_bounds__(256) void zero_deg2(int* __restrict__ dd,
                                                 int* __restrict__ ds) {
    int i = blockIdx.x * 256 + threadIdx.x;
    if (i < N_NODES) { dd[i] = 0; ds[i] = 0; }
}

__global__ __launch_bounds__(256) void hist2_kernel(
        const int* __restrict__ ei, int* __restrict__ dd,
        int* __restrict__ ds) {
    int e = blockIdx.x * 256 + threadIdx.x;
    if (e < E_EDGES) {
        atomicAdd(&dd[ei[E_EDGES + e]], 1);
        atomicAdd(&ds[ei[e]], 1);
    }
}

__global__ __launch_bounds__(256) void scan1_kernel(
        const int* __restrict__ deg, int* __restrict__ rowptr,
        int* __restrict__ bsum) {
    __shared__ int s[256];
    int tid = threadIdx.x;
    int idx = blockIdx.x * 256 + tid;
    int v = (idx < N_NODES) ? deg[idx] : 0;
    s[tid] = v; __syncthreads();
    #pragma unroll
    for (int off = 1; off < 256; off <<= 1) {
        int t = (tid >= off) ? s[tid - off] : 0;
        __syncthreads();
        s[tid] += t;
        __syncthreads();
    }
    if (idx < N_NODES) rowptr[idx] = s[tid] - v;   // exclusive
    if (tid == 255) bsum[blockIdx.x] = s[255];
}

__global__ __launch_bounds__(128) void scan2_kernel(int* __restrict__ bsum,
                                                    int* __restrict__ rowptr) {
    __shared__ int s[128];
    int tid = threadIdx.x;
    int v = (tid < SCAN_BLKS) ? bsum[tid] : 0;
    s[tid] = v; __syncthreads();
    #pragma unroll
    for (int off = 1; off < 128; off <<= 1) {
        int t = (tid >= off) ? s[tid - off] : 0;
        __syncthreads();
        s[tid] += t;
        __syncthreads();
    }
    if (tid < SCAN_BLKS) bsum[tid] = s[tid] - v;   // exclusive
    if (tid == 0) rowptr[N_NODES] = E_EDGES;
}

__global__ __launch_bounds__(256) void scan3_kernel(
        int* __restrict__ rowptr, const int* __restrict__ bsum,
        int* __restrict__ cursor) {
    int idx = blockIdx.x * 256 + threadIdx.x;
    if (idx < N_NODES) {
        int v = rowptr[idx] + bsum[blockIdx.x];
        rowptr[idx] = v;
        cursor[idx] = v;
    }
}

// both scatters fused: dst slot p known in-thread, feeds src-CSR payload
__global__ __launch_bounds__(256) void scatter_both(
        const int* __restrict__ ei, const int* __restrict__ et,
        int* __restrict__ cur_d, int* __restrict__ cur_s,
        int* __restrict__ skey, int* __restrict__ skey_s) {
    int e = blockIdx.x * 256 + threadIdx.x;
    if (e >= E_EDGES) return;
    int s = ei[e], d = ei[E_EDGES + e], rt = et[e];
    int p = atomicAdd(&cur_d[d], 1);
    skey[p] = (s << 6) | rt;                 // dst-order: (src, rel)
    int qp = atomicAdd(&cur_s[s], 1);
    skey_s[qp] = (p << 6) | rt;              // src-order: (dst-slot, rel)
}

// ---- basis [B,K,HID] -> Bt hi/lo [800, Kp] bf16, transposed + zero-padded ----
__global__ __launch_bounds__(256) void split_bt_kernel(
        const float* __restrict__ basis, ushort_t* __restrict__ Bth,
        ushort_t* __restrict__ Btl, int K, int Kp) {
    int idx = blockIdx.x * 256 + threadIdx.x;   // n*Kp + k
    if (idx >= OUTW * Kp) return;
    int n = idx / Kp, k = idx - n * Kp;
    int b = n / HID, o = n - b * HID;
    float v = 0.f;
    if (k < K) v = basis[((size_t)b * K + k) * HID + o];
    ushort_t hi, lo;
    split_f32(v, hi, lo);
    Bth[idx] = hi; Btl[idx] = lo;
}

// ---- MFMA GEMM: C[M,800] = A[M,K] * B[K,800], split-bf16 fp32-accurate ----
// fp32 A staged+split in-kernel; XOR-swizzled 64B LDS rows (conflict-free).
#define BM 128
#define BN 160
__global__ __launch_bounds__(256) void gemm_mfma(
        const float* __restrict__ A,
        const ushort_t* __restrict__ Bth, const ushort_t* __restrict__ Btl,
        float* __restrict__ C, int M, int K, int Kp, int do_relu) {
    __shared__ ushort_t As_h[BM][32], As_l[BM][32];
    __shared__ ushort_t Bs_h[BN][32], Bs_l[BN][32];
    int tid  = threadIdx.x;
    int lane = tid & 63, wave = tid >> 6;
    int ml = lane & 15, quad = lane >> 4;
    int wr = (wave >> 1) * 64, wc = (wave & 1) * 80;
    int row0 = blockIdx.y * BM, col0 = blockIdx.x * BN;
    // A staging role: thread -> (row ra, chunks {half, half+2})
    int ra = tid >> 1, half = tid & 1;
    int gr_a = row0 + ra;
    int sw_a = ra & 3;
    f32x4 acc[4][5] = {};
    int ksteps = Kp >> 5;
    for (int ks = 0; ks < ksteps; ks++) {
        int k0 = ks << 5;
        __syncthreads();
        // ---- stage A: load fp32, relu, split hi/lo, swizzled b128 writes ----
        {
            float vals[16];
            int kb1 = k0 + half * 8;        // chunk c1 = half
            int kb2 = kb1 + 16;             // chunk c2 = half + 2
            if (gr_a < M) {
                const float* ar = A + (size_t)gr_a * K;
                if (kb1 + 8 <= K) {
                    float4 f0 = *(const float4*)&ar[kb1];
                    float4 f1 = *(const float4*)&ar[kb1 + 4];
                    vals[0]=f0.x; vals[1]=f0.y; vals[2]=f0.z; vals[3]=f0.w;
                    vals[4]=f1.x; vals[5]=f1.y; vals[6]=f1.z; vals[7]=f1.w;
                } else {
                    #pragma unroll
                    for (int i = 0; i < 8; i++)
                        vals[i] = (kb1 + i < K) ? ar[kb1 + i] : 0.f;
                }
                if (kb2 + 8 <= K) {
                    float4 f0 = *(const float4*)&ar[kb2];
                    float4 f1 = *(const float4*)&ar[kb2 + 4];
                    vals[8]=f0.x; vals[9]=f0.y; vals[10]=f0.z; vals[11]=f0.w;
                    vals[12]=f1.x; vals[13]=f1.y; vals[14]=f1.z; vals[15]=f1.w;
                } else {
                    #pragma unroll
                    for (int i = 0; i < 8; i++)
                        vals[8 + i] = (kb2 + i < K) ? ar[kb2 + i] : 0.f;
                }
                if (do_relu)
                    #pragma unroll
                    for (int i = 0; i < 16; i++) vals[i] = fmaxf(vals[i], 0.f);
            } else {
                #pragma unroll
                for (int i = 0; i < 16; i++) vals[i] = 0.f;
            }
            ushort8 h1v, l1v, h2v, l2v;
            #pragma unroll
            for (int i = 0; i < 8; i++) {
                ushort_t hh, ll;
                split_f32(vals[i], hh, ll);
                h1v[i] = hh; l1v[i] = ll;
                split_f32(vals[8 + i], hh, ll);
                h2v[i] = hh; l2v[i] = ll;
            }
            int p1 = half ^ sw_a, p2 = (half + 2) ^ sw_a;
            *(ushort8*)&As_h[ra][p1 * 8] = h1v;
            *(ushort8*)&As_l[ra][p1 * 8] = l1v;
            *(ushort8*)&As_h[ra][p2 * 8] = h2v;
            *(ushort8*)&As_l[ra][p2 * 8] = l2v;
        }
        // ---- stage B: 160 rows x 4 chunks = 640 tasks, swizzled writes ----
        for (int t = tid; t < 640; t += 256) {
            int rb = t >> 2, ch = t & 3;
            int ph = ch ^ (rb & 3);
            ushort8 vh = *(const ushort8*)&Bth[(size_t)(col0 + rb) * Kp + k0 + ch * 8];
            ushort8 vl = *(const ushort8*)&Btl[(size_t)(col0 + rb) * Kp + k0 + ch * 8];
            *(ushort8*)&Bs_h[rb][ph * 8] = vh;
            *(ushort8*)&Bs_l[rb][ph * 8] = vl;
        }
        __syncthreads();
        int pq = quad ^ (ml & 3);           // swizzled fragment chunk
        short8 ah[4], al[4], bh[5], bl5[5];
        #pragma unroll
        for (int mt = 0; mt < 4; mt++) {
            int r = wr + mt * 16 + ml;
            ah[mt] = *(const short8*)&As_h[r][pq * 8];
            al[mt] = *(const short8*)&As_l[r][pq * 8];
        }
        #pragma unroll
        for (int nt = 0; nt < 5; nt++) {
            int r = wc + nt * 16 + ml;
            bh[nt]  = *(const short8*)&Bs_h[r][pq * 8];
            bl5[nt] = *(const short8*)&Bs_l[r][pq * 8];
        }
        #pragma unroll
        for (int mt = 0; mt < 4; mt++)
            #pragma unroll
            for (int nt = 0; nt < 5; nt++) {
                acc[mt][nt] = __builtin_amdgcn_mfma_f32_16x16x32_bf16(ah[mt], bh[nt],  acc[mt][nt], 0, 0, 0);
                acc[mt][nt] = __builtin_amdgcn_mfma_f32_16x16x32_bf16(al[mt], bh[nt],  acc[mt][nt], 0, 0, 0);
                acc[mt][nt] = __builtin_amdgcn_mfma_f32_16x16x32_bf16(ah[mt], bl5[nt], acc[mt][nt], 0, 0, 0);
            }
    }
    // epilogue: C/D layout col = lane&15, row = quad*4 + reg
    #pragma unroll
    for (int mt = 0; mt < 4; mt++) {
        #pragma unroll
        for (int nt = 0; nt < 5; nt++) {
            #pragma unroll
            for (int r = 0; r < 4; r++) {
                int grow = row0 + wr + mt * 16 + quad * 4 + r;
                if (grow < M)
                    C[(size_t)grow * OUTW + col0 + wc + nt * 16 + ml] = acc[mt][nt][r];
            }
        }
    }
}

// ---- qb[k*8+b] = sum_o basis[b,k,o]*q[o]; kb likewise ----
__global__ __launch_bounds__(256) void qbkb_kernel(
        const float* __restrict__ basis, const float* __restrict__ q,
        const float* __restrict__ k, float* __restrict__ qb,
        float* __restrict__ kb, int K) {
    int idx = blockIdx.x * 256 + threadIdx.x;
    if (idx >= K * NB) return;
    int kk = idx >> 3, b = idx & 7;
    const float* br = basis + ((size_t)b * K + kk) * HID;
    float aq = 0.f, ak = 0.f;
    for (int o = 0; o < HID; o++) {
        float v = br[o];
        aq = fmaf(v, q[o], aq);
        ak = fmaf(v, k[o], ak);
    }
    qb[idx] = aq; kb[idx] = ak;
}

// ---- xbq[n,b] = sum_k in[n,k]*qb[k,b] (reads input, not xb) ----
__global__ __launch_bounds__(256) void qk2_kernel(
        const float* __restrict__ x, const float* __restrict__ qb,
        const float* __restrict__ kb, float* __restrict__ xbq,
        float* __restrict__ xbk, int K, int do_relu) {
    __shared__ float sqb[320 * NB], skb[320 * NB];
    int tid = threadIdx.x;
    for (int i = tid; i < K * NB; i += 256) { sqb[i] = qb[i]; skb[i] = kb[i]; }
    __syncthreads();
    int idx = blockIdx.x * 256 + tid;     // n*8 + b
    if (idx >= N_NODES * NB) return;
    int n = idx >> 3, b = idx & 7;
    const float* xr = x + (size_t)n * K;
    float aq = 0.f, ak = 0.f;
    for (int kk = 0; kk < K; kk++) {
        float v = xr[kk];
        if (do_relu) v = fmaxf(v, 0.f);
        aq = fmaf(v, sqb[kk * NB + b], aq);
        ak = fmaf(v, skb[kk * NB + b], ak);
    }
    xbq[idx] = aq;
    xbk[idx] = ak;
}

// ==== src-major: Z[dstslot,:] = sum_b comp[rt,b]*xb[s,b,:]  (bf16 out) ====
__global__ __launch_bounds__(256) void compute_z(
        const int* __restrict__ rowptr_s, const int* __restrict__ skey_s,
        const float* __restrict__ comp, const float* __restrict__ xb,
        ushort_t* __restrict__ Z) {
    int wave = threadIdx.x >> 6, lane = threadIdx.x & 63;
    int s = blockIdx.x * 4 + wave;
    if (s >= N_NODES) return;
    int beg = rowptr_s[s], end = rowptr_s[s + 1];
    if (beg == end) return;
    int o = lane * 2;
    f32x2 xrow[NB];
    if (lane < 50) {
        #pragma unroll
        for (int b = 0; b < NB; b++)
            xrow[b] = *(const f32x2*)&xb[(size_t)s * OUTW + b * HID + o];
    }
    for (int p = beg; p < end; p++) {
        int key = skey_s[p];
        int zpos = key >> 6, rt = key & 63;
        const float* cr = comp + rt * NB;
        if (lane < 50) {
            f32x2 z = {0.f, 0.f};
            #pragma unroll
            for (int b = 0; b < NB; b++) z += cr[b] * xrow[b];
            ushort2 zz;
            zz.x = f2bf_rne(z.x);
            zz.y = f2bf_rne(z.y);
            *(ushort2*)&Z[(size_t)zpos * HID + o] = zz;
        }
    }
}

// ==== dst-major: online softmax + streaming Z accumulation + bias ====
__global__ __launch_bounds__(256) void msg_soft(
        const int* __restrict__ rowptr, const int* __restrict__ skey,
        const float* __restrict__ comp, const ushort_t* __restrict__ Z,
        const float* __restrict__ xbq, const float* __restrict__ xbk,
        const float* __restrict__ bias, float* __restrict__ h) {
    int wave = threadIdx.x >> 6, lane = threadIdx.x & 63;
    int d = blockIdx.x * 4 + wave;
    if (d >= N_NODES) return;
    int beg = rowptr[d], end = rowptr[d + 1];

    float4 qd0 = *(const float4*)&xbq[d * NB];
    float4 qd1 = *(const float4*)&xbq[d * NB + 4];

    f32x2 acc = {0.f, 0.f};
    float m = -1e30f, l = 0.f;
    int o = lane * 2;

    for (int c0 = beg; c0 < end; c0 += 64) {
        int p = c0 + lane;
        bool valid = p < end;
        float a = -1e30f;
        if (valid) {
            int key = skey[p];
            int s = key >> 6, rt = key & 63;
            const float4 c0v = *(const float4*)&comp[rt * NB];
            const float4 c1v = *(const float4*)&comp[rt * NB + 4];
            const float4 k0v = *(const float4*)&xbk[s * NB];
            const float4 k1v = *(const float4*)&xbk[s * NB + 4];
            float qi = c0v.x*qd0.x + c0v.y*qd0.y + c0v.z*qd0.z + c0v.w*qd0.w
                     + c1v.x*qd1.x + c1v.y*qd1.y + c1v.z*qd1.z + c1v.w*qd1.w;
            float kj = c0v.x*k0v.x + c0v.y*k0v.y + c0v.z*k0v.z + c0v.w*k0v.w
                     + c1v.x*k1v.x + c1v.y*k1v.y + c1v.z*k1v.z + c1v.w*k1v.w;
            a = qi + kj;
            a = a > 0.f ? a : 0.2f * a;     // leaky_relu 0.2
        }
        float cm = a;
        #pragma unroll
        for (int off = 32; off; off >>= 1) cm = fmaxf(cm, __shfl_xor(cm, off));
        float M = fmaxf(m, cm);
        float scale = __expf(m - M);
        acc *= scale; l *= scale; m = M;
        float wgt = valid ? __expf(a - M) : 0.f;
        float cs = wgt;
        #pragma unroll
        for (int off = 32; off; off >>= 1) cs += __shfl_xor(cs, off);
        l += cs;
        int cnt = end - c0; if (cnt > 64) cnt = 64;
        for (int j = 0; j < cnt; j++) {
            float wj = __shfl(wgt, j);
            if (lane < 50) {
                ushort2 zz = *(const ushort2*)&Z[(size_t)(c0 + j) * HID + o];
                f32x2 zv = {bf2f(zz.x), bf2f(zz.y)};
                acc += wj * zv;
            }
        }
    }
    if (lane < 50) {
        float inv = 1.f / (l + 1e-16f);
        f32x2 r;
        r.x = bias[o]     + acc.x * inv;
        r.y = bias[o + 1] + acc.y * inv;
        *(f32x2*)&h[(size_t)d * HID + o] = r;
    }
}

// ---- pooled = mean(relu(h2[qidx])); out = pooled @ Wl^T + bl ----
__global__ __launch_bounds__(128) void head_kernel(
        const float* __restrict__ h2, const int* __restrict__ qidx,
        const float* __restrict__ Wl, const float* __restrict__ bl,
        float* __restrict__ out) {
    __shared__ float pooled[HID];
    int tid = threadIdx.x;
    if (tid < HID) {
        float s = 0.f;
        for (int i = 0; i < NQ; i++)
            s += fmaxf(h2[(size_t)qidx[i] * HID + tid], 0.f);
        pooled[tid] = s * (1.0f / NQ);
    }
    __syncthreads();
    if (tid < CLS) {
        float s = bl[tid];
        for (int o = 0; o < HID; o++) s = fmaf(pooled[o], Wl[tid * HID + o], s);
        out[tid] = s;
    }
}

extern "C" void kernel_launch(void* const* d_in, const int* in_sizes, int n_in,
                              void* d_out, int out_size, void* d_ws, size_t ws_size,
                              hipStream_t stream) {
    const float* x      = (const float*)d_in[0];
    const int*   ei     = (const int*)  d_in[1];
    const int*   et     = (const int*)  d_in[2];
    const int*   qidx   = (const int*)  d_in[3];
    const float* comp1  = (const float*)d_in[4];
    const float* basis1 = (const float*)d_in[5];
    const float* q1     = (const float*)d_in[6];
    const float* k1     = (const float*)d_in[7];
    const float* b1     = (const float*)d_in[8];
    const float* comp2  = (const float*)d_in[9];
    const float* basis2 = (const float*)d_in[10];
    const float* q2     = (const float*)d_in[11];
    const float* k2     = (const float*)d_in[12];
    const float* b2     = (const float*)d_in[13];
    const float* Wl     = (const float*)d_in[14];
    const float* bl     = (const float*)d_in[15];
    float* out = (float*)d_out;

    const int KP1 = 320, KP2 = 128;

    char* w = (char*)d_ws;
    size_t off = 0;
    auto alloc = [&](size_t nbytes) {
        void* p = (void*)(w + off);
        off += ((nbytes + 255) / 256) * 256;
        return p;
    };
    float*    xb     = (float*)alloc((size_t)N_NODES * OUTW * 4);   // 64 MB
    ushort_t* Z      = (ushort_t*)alloc((size_t)E_EDGES * HID * 2); // 64 MB
    float*    h1     = (float*)alloc((size_t)N_NODES * HID * 4);    // 8 MB
    float*    h2     = (float*)alloc((size_t)N_NODES * HID * 4);    // 8 MB
    ushort_t* Bth    = (ushort_t*)alloc((size_t)OUTW * KP1 * 2);
    ushort_t* Btl    = (ushort_t*)alloc((size_t)OUTW * KP1 * 2);
    float*    xbq    = (float*)alloc((size_t)N_NODES * NB * 4);
    float*    xbk    = (float*)alloc((size_t)N_NODES * NB * 4);
    float*    qb     = (float*)alloc((size_t)KP1 * NB * 4);
    float*    kb     = (float*)alloc((size_t)KP1 * NB * 4);
    int*      deg_d  = (int*)alloc(N_NODES * 4);
    int*      deg_s  = (int*)alloc(N_NODES * 4);
    int*      rp_d   = (int*)alloc((N_NODES + 1) * 4);
    int*      rp_s   = (int*)alloc((N_NODES + 1) * 4);
    int*      cur_d  = (int*)alloc(N_NODES * 4);
    int*      cur_s  = (int*)alloc(N_NODES * 4);
    int*      bsum   = (int*)alloc(SCAN_BLKS * 4);
    int*      skey   = (int*)alloc(E_EDGES * 4);
    int*      skey_s = (int*)alloc(E_EDGES * 4);

    // ---- CSR build (once; same graph both layers) ----
    zero_deg2<<<SCAN_BLKS, 256, 0, stream>>>(deg_d, deg_s);
    hist2_kernel<<<(E_EDGES + 255) / 256, 256, 0, stream>>>(ei, deg_d, deg_s);
    scan1_kernel<<<SCAN_BLKS, 256, 0, stream>>>(deg_d, rp_d, bsum);
    scan2_kernel<<<1, 128, 0, stream>>>(bsum, rp_d);
    scan3_kernel<<<SCAN_BLKS, 256, 0, stream>>>(rp_d, bsum, cur_d);
    scan1_kernel<<<SCAN_BLKS, 256, 0, stream>>>(deg_s, rp_s, bsum);
    scan2_kernel<<<1, 128, 0, stream>>>(bsum, rp_s);
    scan3_kernel<<<SCAN_BLKS, 256, 0, stream>>>(rp_s, bsum, cur_s);
    scatter_both<<<(E_EDGES + 255) / 256, 256, 0, stream>>>(ei, et, cur_d, cur_s, skey, skey_s);

    auto layer = [&](const float* input, int K, int Kp, int relu_in,
                     const float* comp, const float* basis, const float* q,
                     const float* k, const float* bias, float* hout) {
        int nb = OUTW * Kp;
        split_bt_kernel<<<(nb + 255) / 256, 256, 0, stream>>>(basis, Bth, Btl, K, Kp);
        dim3 g(OUTW / BN, (N_NODES + BM - 1) / BM);
        gemm_mfma<<<g, 256, 0, stream>>>(input, Bth, Btl, xb, N_NODES, K, Kp, relu_in);
        qbkb_kernel<<<(K * NB + 255) / 256, 256, 0, stream>>>(basis, q, k, qb, kb, K);
        qk2_kernel<<<(N_NODES * NB + 255) / 256, 256, 0, stream>>>(input, qb, kb, xbq, xbk, K, relu_in);
        compute_z<<<(N_NODES + 3) / 4, 256, 0, stream>>>(rp_s, skey_s, comp, xb, Z);
        msg_soft<<<(N_NODES + 3) / 4, 256, 0, stream>>>(rp_d, skey, comp, Z, xbq, xbk, bias, hout);
    };

    layer(x,  IN_CH, KP1, 0, comp1, basis1, q1, k1, b1, h1);
    layer(h1, HID,   KP2, 1, comp2, basis2, q2, k2, b2, h2);
    head_kernel<<<1, 128, 0, stream>>>(h2, qidx, Wl, bl, out);
}

// Round 6
// 439.509 us; speedup vs baseline: 2.0536x; 1.0886x over previous
//
#include <hip/hip_runtime.h>
#include <math.h>

#define N_NODES 20000
#define E_EDGES 320000
#define IN_CH   300
#define HID     100
#define R_REL   50
#define NB      8
#define CLS     3
#define NQ      64
#define OUTW    800   // NB * HID
#define ZW      128   // padded Z row stride (ushorts) -> 256B-aligned rows
#define SCAN_BLKS ((N_NODES + 255) / 256)   // 79

typedef unsigned short ushort_t;
typedef __attribute__((ext_vector_type(8))) short     short8;
typedef __attribute__((ext_vector_type(8))) unsigned short ushort8;
typedef __attribute__((ext_vector_type(4))) float     f32x4;
typedef __attribute__((ext_vector_type(2))) float     f32x2;

__device__ __forceinline__ ushort_t f2bf_rne(float f) {   // round-nearest-even
    unsigned u = __float_as_uint(f);
    unsigned r = (u + 0x7fffu + ((u >> 16) & 1u)) >> 16;
    return (ushort_t)r;
}
__device__ __forceinline__ float bf2f(ushort_t u) {
    return __uint_as_float((unsigned)u << 16);
}

// ============================ CSR build =================================
__global__ __launch_bounds__(256) void zero_deg2(int* __restrict__ dd,
                                                 int* __restrict__ ds) {
    int i = blockIdx.x * 256 + threadIdx.x;
    if (i < N_NODES) { dd[i] = 0; ds[i] = 0; }
}

__global__ __launch_bounds__(256) void hist2_kernel(
        const int* __restrict__ ei, int* __restrict__ dd,
        int* __restrict__ ds) {
    int e = blockIdx.x * 256 + threadIdx.x;
    if (e < E_EDGES) {
        atomicAdd(&dd[ei[E_EDGES + e]], 1);
        atomicAdd(&ds[ei[e]], 1);
    }
}

__global__ __launch_bounds__(256) void scan1_kernel(
        const int* __restrict__ deg, int* __restrict__ rowptr,
        int* __restrict__ bsum) {
    __shared__ int s[256];
    int tid = threadIdx.x;
    int idx = blockIdx.x * 256 + tid;
    int v = (idx < N_NODES) ? deg[idx] : 0;
    s[tid] = v; __syncthreads();
    #pragma unroll
    for (int off = 1; off < 256; off <<= 1) {
        int t = (tid >= off) ? s[tid - off] : 0;
        __syncthreads();
        s[tid] += t;
        __syncthreads();
    }
    if (idx < N_NODES) rowptr[idx] = s[tid] - v;   // exclusive
    if (tid == 255) bsum[blockIdx.x] = s[255];
}

__global__ __launch_bounds__(128) void scan2_kernel(int* __restrict__ bsum,
                                                    int* __restrict__ rowptr) {
    __shared__ int s[128];
    int tid = threadIdx.x;
    int v = (tid < SCAN_BLKS) ? bsum[tid] : 0;
    s[tid] = v; __syncthreads();
    #pragma unroll
    for (int off = 1; off < 128; off <<= 1) {
        int t = (tid >= off) ? s[tid - off] : 0;
        __syncthreads();
        s[tid] += t;
        __syncthreads();
    }
    if (tid < SCAN_BLKS) bsum[tid] = s[tid] - v;   // exclusive
    if (tid == 0) rowptr[N_NODES] = E_EDGES;
}

__global__ __launch_bounds__(256) void scan3_kernel(
        int* __restrict__ rowptr, const int* __restrict__ bsum,
        int* __restrict__ cursor) {
    int idx = blockIdx.x * 256 + threadIdx.x;
    if (idx < N_NODES) {
        int v = rowptr[idx] + bsum[blockIdx.x];
        rowptr[idx] = v;
        cursor[idx] = v;
    }
}

// both scatters fused: dst slot p known in-thread, feeds src-CSR payload
__global__ __launch_bounds__(256) void scatter_both(
        const int* __restrict__ ei, const int* __restrict__ et,
        int* __restrict__ cur_d, int* __restrict__ cur_s,
        int* __restrict__ skey, int* __restrict__ skey_s) {
    int e = blockIdx.x * 256 + threadIdx.x;
    if (e >= E_EDGES) return;
    int s = ei[e], d = ei[E_EDGES + e], rt = et[e];
    int p = atomicAdd(&cur_d[d], 1);
    skey[p] = (s << 6) | rt;                 // dst-order: (src, rel)
    int qp = atomicAdd(&cur_s[s], 1);
    skey_s[qp] = (p << 6) | rt;              // src-order: (dst-slot, rel)
}

// ---- basis [B,K,HID] -> Bt [800, Kp] bf16 RNE, transposed + zero-padded ----
__global__ __launch_bounds__(256) void split_bt_kernel(
        const float* __restrict__ basis, ushort_t* __restrict__ Bt,
        int K, int Kp) {
    int idx = blockIdx.x * 256 + threadIdx.x;   // n*Kp + k
    if (idx >= OUTW * Kp) return;
    int n = idx / Kp, k = idx - n * Kp;
    int b = n / HID, o = n - b * HID;
    float v = 0.f;
    if (k < K) v = basis[((size_t)b * K + k) * HID + o];
    Bt[idx] = f2bf_rne(v);
}

// ---- MFMA GEMM: C[M,800] = A[M,K] * B[K,800], single bf16 RNE ----
// fp32 A staged+converted in-kernel; XOR-swizzled 64B LDS rows.
#define BM 128
#define BN 160
__global__ __launch_bounds__(256) void gemm_mfma(
        const float* __restrict__ A, const ushort_t* __restrict__ Bt,
        float* __restrict__ C, int M, int K, int Kp, int do_relu) {
    __shared__ ushort_t As[BM][32];
    __shared__ ushort_t Bs[BN][32];
    int tid  = threadIdx.x;
    int lane = tid & 63, wave = tid >> 6;
    int ml = lane & 15, quad = lane >> 4;
    int wr = (wave >> 1) * 64, wc = (wave & 1) * 80;
    int row0 = blockIdx.y * BM, col0 = blockIdx.x * BN;
    // A staging role: thread -> (row ra, chunks {half, half+2})
    int ra = tid >> 1, half = tid & 1;
    int gr_a = row0 + ra;
    int sw_a = ra & 3;
    f32x4 acc[4][5] = {};
    int ksteps = Kp >> 5;
    for (int ks = 0; ks < ksteps; ks++) {
        int k0 = ks << 5;
        __syncthreads();
        // ---- stage A: load fp32, relu, RNE->bf16, swizzled b128 writes ----
        {
            float vals[16];
            int kb1 = k0 + half * 8;        // chunk c1 = half
            int kb2 = kb1 + 16;             // chunk c2 = half + 2
            if (gr_a < M) {
                const float* ar = A + (size_t)gr_a * K;
                if (kb1 + 8 <= K) {
                    float4 f0 = *(const float4*)&ar[kb1];
                    float4 f1 = *(const float4*)&ar[kb1 + 4];
                    vals[0]=f0.x; vals[1]=f0.y; vals[2]=f0.z; vals[3]=f0.w;
                    vals[4]=f1.x; vals[5]=f1.y; vals[6]=f1.z; vals[7]=f1.w;
                } else {
                    #pragma unroll
                    for (int i = 0; i < 8; i++)
                        vals[i] = (kb1 + i < K) ? ar[kb1 + i] : 0.f;
                }
                if (kb2 + 8 <= K) {
                    float4 f0 = *(const float4*)&ar[kb2];
                    float4 f1 = *(const float4*)&ar[kb2 + 4];
                    vals[8]=f0.x; vals[9]=f0.y; vals[10]=f0.z; vals[11]=f0.w;
                    vals[12]=f1.x; vals[13]=f1.y; vals[14]=f1.z; vals[15]=f1.w;
                } else {
                    #pragma unroll
                    for (int i = 0; i < 8; i++)
                        vals[8 + i] = (kb2 + i < K) ? ar[kb2 + i] : 0.f;
                }
                if (do_relu)
                    #pragma unroll
                    for (int i = 0; i < 16; i++) vals[i] = fmaxf(vals[i], 0.f);
            } else {
                #pragma unroll
                for (int i = 0; i < 16; i++) vals[i] = 0.f;
            }
            ushort8 h1v, h2v;
            #pragma unroll
            for (int i = 0; i < 8; i++) {
                h1v[i] = f2bf_rne(vals[i]);
                h2v[i] = f2bf_rne(vals[8 + i]);
            }
            int p1 = half ^ sw_a, p2 = (half + 2) ^ sw_a;
            *(ushort8*)&As[ra][p1 * 8] = h1v;
            *(ushort8*)&As[ra][p2 * 8] = h2v;
        }
        // ---- stage B: 160 rows x 4 chunks = 640 tasks, swizzled writes ----
        for (int t = tid; t < 640; t += 256) {
            int rb = t >> 2, ch = t & 3;
            int ph = ch ^ (rb & 3);
            ushort8 vh = *(const ushort8*)&Bt[(size_t)(col0 + rb) * Kp + k0 + ch * 8];
            *(ushort8*)&Bs[rb][ph * 8] = vh;
        }
        __syncthreads();
        int pq = quad ^ (ml & 3);           // swizzled fragment chunk
        short8 af[4], bf[5];
        #pragma unroll
        for (int mt = 0; mt < 4; mt++)
            af[mt] = *(const short8*)&As[wr + mt * 16 + ml][pq * 8];
        #pragma unroll
        for (int nt = 0; nt < 5; nt++)
            bf[nt] = *(const short8*)&Bs[wc + nt * 16 + ml][pq * 8];
        #pragma unroll
        for (int mt = 0; mt < 4; mt++)
            #pragma unroll
            for (int nt = 0; nt < 5; nt++)
                acc[mt][nt] = __builtin_amdgcn_mfma_f32_16x16x32_bf16(af[mt], bf[nt], acc[mt][nt], 0, 0, 0);
    }
    // epilogue: C/D layout col = lane&15, row = quad*4 + reg
    #pragma unroll
    for (int mt = 0; mt < 4; mt++) {
        #pragma unroll
        for (int nt = 0; nt < 5; nt++) {
            #pragma unroll
            for (int r = 0; r < 4; r++) {
                int grow = row0 + wr + mt * 16 + quad * 4 + r;
                if (grow < M)
                    C[(size_t)grow * OUTW + col0 + wc + nt * 16 + ml] = acc[mt][nt][r];
            }
        }
    }
}

// ---- qb[k*8+b] = sum_o basis[b,k,o]*q[o]; kb likewise ----
__global__ __launch_bounds__(256) void qbkb_kernel(
        const float* __restrict__ basis, const float* __restrict__ q,
        const float* __restrict__ k, float* __restrict__ qb,
        float* __restrict__ kb, int K) {
    int idx = blockIdx.x * 256 + threadIdx.x;
    if (idx >= K * NB) return;
    int kk = idx >> 3, b = idx & 7;
    const float* br = basis + ((size_t)b * K + kk) * HID;
    float aq = 0.f, ak = 0.f;
    for (int o = 0; o < HID; o++) {
        float v = br[o];
        aq = fmaf(v, q[o], aq);
        ak = fmaf(v, k[o], ak);
    }
    qb[idx] = aq; kb[idx] = ak;
}

// ---- xbq[n,b] = sum_k in[n,k]*qb[k,b] (reads input, not xb) ----
__global__ __launch_bounds__(256) void qk2_kernel(
        const float* __restrict__ x, const float* __restrict__ qb,
        const float* __restrict__ kb, float* __restrict__ xbq,
        float* __restrict__ xbk, int K, int do_relu) {
    __shared__ float sqb[320 * NB], skb[320 * NB];
    int tid = threadIdx.x;
    for (int i = tid; i < K * NB; i += 256) { sqb[i] = qb[i]; skb[i] = kb[i]; }
    __syncthreads();
    int idx = blockIdx.x * 256 + tid;     // idx = n*8 + b
    if (idx >= N_NODES * NB) return;
    int n = idx >> 3, b = idx & 7;
    const float* xr = x + (size_t)n * K;
    float aq = 0.f, ak = 0.f;
    for (int kk = 0; kk < K; kk++) {
        float v = xr[kk];
        if (do_relu) v = fmaxf(v, 0.f);
        aq = fmaf(v, sqb[kk * NB + b], aq);
        ak = fmaf(v, skb[kk * NB + b], ak);
    }
    xbq[idx] = aq;
    xbk[idx] = ak;
}

// ==== src-major: Z[dstslot,:] = sum_b comp[rt,b]*xb[s,b,:]  (bf16 out) ====
__global__ __launch_bounds__(256) void compute_z(
        const int* __restrict__ rowptr_s, const int* __restrict__ skey_s,
        const float* __restrict__ comp, const float* __restrict__ xb,
        ushort_t* __restrict__ Z) {
    int wave = threadIdx.x >> 6, lane = threadIdx.x & 63;
    int s = blockIdx.x * 4 + wave;
    if (s >= N_NODES) return;
    int beg = rowptr_s[s], end = rowptr_s[s + 1];
    if (beg == end) return;
    int o = lane * 2;
    f32x2 xrow[NB];
    if (lane < 50) {
        #pragma unroll
        for (int b = 0; b < NB; b++)
            xrow[b] = *(const f32x2*)&xb[(size_t)s * OUTW + b * HID + o];
    }
    for (int p = beg; p < end; p++) {
        int key = skey_s[p];
        int zpos = key >> 6, rt = key & 63;
        const float* cr = comp + rt * NB;
        if (lane < 50) {
            f32x2 z = {0.f, 0.f};
            #pragma unroll
            for (int b = 0; b < NB; b++) z += cr[b] * xrow[b];
            ushort2 zz;
            zz.x = f2bf_rne(z.x);
            zz.y = f2bf_rne(z.y);
            *(ushort2*)&Z[(size_t)zpos * ZW + o] = zz;
        }
    }
}

// ==== dst-major: online softmax + streaming Z accumulation + bias ====
__global__ __launch_bounds__(256) void msg_soft(
        const int* __restrict__ rowptr, const int* __restrict__ skey,
        const float* __restrict__ comp, const ushort_t* __restrict__ Z,
        const float* __restrict__ xbq, const float* __restrict__ xbk,
        const float* __restrict__ bias, float* __restrict__ h) {
    int wave = threadIdx.x >> 6, lane = threadIdx.x & 63;
    int d = blockIdx.x * 4 + wave;
    if (d >= N_NODES) return;
    int beg = rowptr[d], end = rowptr[d + 1];

    float4 qd0 = *(const float4*)&xbq[d * NB];
    float4 qd1 = *(const float4*)&xbq[d * NB + 4];

    f32x2 acc = {0.f, 0.f};
    float m = -1e30f, l = 0.f;
    int o = lane * 2;

    for (int c0 = beg; c0 < end; c0 += 64) {
        int p = c0 + lane;
        bool valid = p < end;
        float a = -1e30f;
        if (valid) {
            int key = skey[p];
            int s = key >> 6, rt = key & 63;
            const float4 c0v = *(const float4*)&comp[rt * NB];
            const float4 c1v = *(const float4*)&comp[rt * NB + 4];
            const float4 k0v = *(const float4*)&xbk[s * NB];
            const float4 k1v = *(const float4*)&xbk[s * NB + 4];
            float qi = c0v.x*qd0.x + c0v.y*qd0.y + c0v.z*qd0.z + c0v.w*qd0.w
                     + c1v.x*qd1.x + c1v.y*qd1.y + c1v.z*qd1.z + c1v.w*qd1.w;
            float kj = c0v.x*k0v.x + c0v.y*k0v.y + c0v.z*k0v.z + c0v.w*k0v.w
                     + c1v.x*k1v.x + c1v.y*k1v.y + c1v.z*k1v.z + c1v.w*k1v.w;
            a = qi + kj;
            a = a > 0.f ? a : 0.2f * a;     // leaky_relu 0.2
        }
        float cm = a;
        #pragma unroll
        for (int off = 32; off; off >>= 1) cm = fmaxf(cm, __shfl_xor(cm, off));
        float M = fmaxf(m, cm);
        float scale = __expf(m - M);
        acc *= scale; l *= scale; m = M;
        float wgt = valid ? __expf(a - M) : 0.f;
        float cs = wgt;
        #pragma unroll
        for (int off = 32; off; off >>= 1) cs += __shfl_xor(cs, off);
        l += cs;
        int cnt = end - c0; if (cnt > 64) cnt = 64;
        for (int j = 0; j < cnt; j++) {
            float wj = __shfl(wgt, j);
            if (lane < 50) {
                ushort2 zz = *(const ushort2*)&Z[(size_t)(c0 + j) * ZW + o];
                f32x2 zv = {bf2f(zz.x), bf2f(zz.y)};
                acc += wj * zv;
            }
        }
    }
    if (lane < 50) {
        float inv = 1.f / (l + 1e-16f);
        f32x2 r;
        r.x = bias[o]     + acc.x * inv;
        r.y = bias[o + 1] + acc.y * inv;
        *(f32x2*)&h[(size_t)d * HID + o] = r;
    }
}

// ---- pooled = mean(relu(h2[qidx])); out = pooled @ Wl^T + bl ----
__global__ __launch_bounds__(128) void head_kernel(
        const float* __restrict__ h2, const int* __restrict__ qidx,
        const float* __restrict__ Wl, const float* __restrict__ bl,
        float* __restrict__ out) {
    __shared__ float pooled[HID];
    int tid = threadIdx.x;
    if (tid < HID) {
        float s = 0.f;
        for (int i = 0; i < NQ; i++)
            s += fmaxf(h2[(size_t)qidx[i] * HID + tid], 0.f);
        pooled[tid] = s * (1.0f / NQ);
    }
    __syncthreads();
    if (tid < CLS) {
        float s = bl[tid];
        for (int o = 0; o < HID; o++) s = fmaf(pooled[o], Wl[tid * HID + o], s);
        out[tid] = s;
    }
}

extern "C" void kernel_launch(void* const* d_in, const int* in_sizes, int n_in,
                              void* d_out, int out_size, void* d_ws, size_t ws_size,
                              hipStream_t stream) {
    const float* x      = (const float*)d_in[0];
    const int*   ei     = (const int*)  d_in[1];
    const int*   et     = (const int*)  d_in[2];
    const int*   qidx   = (const int*)  d_in[3];
    const float* comp1  = (const float*)d_in[4];
    const float* basis1 = (const float*)d_in[5];
    const float* q1     = (const float*)d_in[6];
    const float* k1     = (const float*)d_in[7];
    const float* b1     = (const float*)d_in[8];
    const float* comp2  = (const float*)d_in[9];
    const float* basis2 = (const float*)d_in[10];
    const float* q2     = (const float*)d_in[11];
    const float* k2     = (const float*)d_in[12];
    const float* b2     = (const float*)d_in[13];
    const float* Wl     = (const float*)d_in[14];
    const float* bl     = (const float*)d_in[15];
    float* out = (float*)d_out;

    const int KP1 = 320, KP2 = 128;

    char* w = (char*)d_ws;
    size_t off = 0;
    auto alloc = [&](size_t nbytes) {
        void* p = (void*)(w + off);
        off += ((nbytes + 255) / 256) * 256;
        return p;
    };
    float*    xb     = (float*)alloc((size_t)N_NODES * OUTW * 4);   // 64 MB
    ushort_t* Z      = (ushort_t*)alloc((size_t)E_EDGES * ZW * 2);  // 82 MB
    float*    h1     = (float*)alloc((size_t)N_NODES * HID * 4);    // 8 MB
    float*    h2     = (float*)alloc((size_t)N_NODES * HID * 4);    // 8 MB
    ushort_t* Bt     = (ushort_t*)alloc((size_t)OUTW * KP1 * 2);    // 0.5 MB
    float*    xbq    = (float*)alloc((size_t)N_NODES * NB * 4);
    float*    xbk    = (float*)alloc((size_t)N_NODES * NB * 4);
    float*    qb     = (float*)alloc((size_t)KP1 * NB * 4);
    float*    kb     = (float*)alloc((size_t)KP1 * NB * 4);
    int*      deg_d  = (int*)alloc(N_NODES * 4);
    int*      deg_s  = (int*)alloc(N_NODES * 4);
    int*      rp_d   = (int*)alloc((N_NODES + 1) * 4);
    int*      rp_s   = (int*)alloc((N_NODES + 1) * 4);
    int*      cur_d  = (int*)alloc(N_NODES * 4);
    int*      cur_s  = (int*)alloc(N_NODES * 4);
    int*      bsum   = (int*)alloc(SCAN_BLKS * 4);
    int*      skey   = (int*)alloc(E_EDGES * 4);
    int*      skey_s = (int*)alloc(E_EDGES * 4);

    // ---- CSR build (once; same graph both layers) ----
    zero_deg2<<<SCAN_BLKS, 256, 0, stream>>>(deg_d, deg_s);
    hist2_kernel<<<(E_EDGES + 255) / 256, 256, 0, stream>>>(ei, deg_d, deg_s);
    scan1_kernel<<<SCAN_BLKS, 256, 0, stream>>>(deg_d, rp_d, bsum);
    scan2_kernel<<<1, 128, 0, stream>>>(bsum, rp_d);
    scan3_kernel<<<SCAN_BLKS, 256, 0, stream>>>(rp_d, bsum, cur_d);
    scan1_kernel<<<SCAN_BLKS, 256, 0, stream>>>(deg_s, rp_s, bsum);
    scan2_kernel<<<1, 128, 0, stream>>>(bsum, rp_s);
    scan3_kernel<<<SCAN_BLKS, 256, 0, stream>>>(rp_s, bsum, cur_s);
    scatter_both<<<(E_EDGES + 255) / 256, 256, 0, stream>>>(ei, et, cur_d, cur_s, skey, skey_s);

    auto layer = [&](const float* input, int K, int Kp, int relu_in,
                     const float* comp, const float* basis, const float* q,
                     const float* k, const float* bias, float* hout) {
        int nb = OUTW * Kp;
        split_bt_kernel<<<(nb + 255) / 256, 256, 0, stream>>>(basis, Bt, K, Kp);
        dim3 g(OUTW / BN, (N_NODES + BM - 1) / BM);
        gemm_mfma<<<g, 256, 0, stream>>>(input, Bt, xb, N_NODES, K, Kp, relu_in);
        qbkb_kernel<<<(K * NB + 255) / 256, 256, 0, stream>>>(basis, q, k, qb, kb, K);
        qk2_kernel<<<(N_NODES * NB + 255) / 256, 256, 0, stream>>>(input, qb, kb, xbq, xbk, K, relu_in);
        compute_z<<<(N_NODES + 3) / 4, 256, 0, stream>>>(rp_s, skey_s, comp, xb, Z);
        msg_soft<<<(N_NODES + 3) / 4, 256, 0, stream>>>(rp_d, skey, comp, Z, xbq, xbk, bias, hout);
    };

    layer(x,  IN_CH, KP1, 0, comp1, basis1, q1, k1, b1, h1);
    layer(h1, HID,   KP2, 1, comp2, basis2, q2, k2, b2, h2);
    head_kernel<<<1, 128, 0, stream>>>(h2, qidx, Wl, bl, out);
}